// Round 5
// baseline (717.701 us; speedup 1.0000x reference)
//
#include <hip/hip_runtime.h>
#include <hip/hip_bf16.h>
#include <math.h>

#define HID     2560
#define D_INNER 8192
#define NG      32
#define D_SSM   4096
#define KCONV   4
#define HD      128
#define DS      64
#define LSEQ    1024
#define LC      64
#define NC      (LSEQ / LC)
#define NZ      4224          // z(4096) + dt(32) + D(32) + pad(64)
#define NBIG    12416         // qkv(8192) + NZ
#define EPS_RMS 1e-6f

#define BKT     32            // K per tile (one 16x16x32 MFMA k-depth)

typedef short bf16x8 __attribute__((ext_vector_type(8)));
typedef float f32x4 __attribute__((ext_vector_type(4)));

__device__ __forceinline__ float siluf(float x) { return x / (1.f + expf(-x)); }

__device__ __forceinline__ unsigned short f2bf(float x) {
    __hip_bfloat16 b = __float2bfloat16(x);
    return *reinterpret_cast<unsigned short*>(&b);
}
__device__ __forceinline__ float bf2f(unsigned short u) {
    union { unsigned int i; float f; } v;
    v.i = ((unsigned int)u) << 16;
    return v.f;
}

__device__ __forceinline__ void async16(const ushort* g, ushort* l) {
    __builtin_amdgcn_global_load_lds(
        (const __attribute__((address_space(1))) unsigned int*)g,
        (__attribute__((address_space(3))) unsigned int*)l, 16, 0, 0);
}

// counted-vmcnt gate: wave drains its own ds_reads (lgkmcnt 0) but leaves VM
// staging loads in flight across the raw barrier (T4). Compile-time VM only.
template<int VM>
__device__ __forceinline__ void gate_barrier() {
    asm volatile("s_waitcnt vmcnt(%0) lgkmcnt(0)" :: "n"(VM) : "memory");
    __builtin_amdgcn_s_barrier();
    asm volatile("" ::: "memory");
}

// ---------------- f32 -> (hi, lo) bf16 planes ----------------
__global__ __launch_bounds__(256)
void split_cvt(const float4* __restrict__ in, ushort4* __restrict__ hi,
               ushort4* __restrict__ lo, int n4) {
    int i = blockIdx.x * 256 + threadIdx.x;
    if (i >= n4) return;
    float4 v = in[i];
    ushort4 h, l;
    h.x = f2bf(v.x); l.x = f2bf(v.x - bf2f(h.x));
    h.y = f2bf(v.y); l.y = f2bf(v.y - bf2f(h.y));
    h.z = f2bf(v.z); l.z = f2bf(v.z - bf2f(h.z));
    h.w = f2bf(v.w); l.w = f2bf(v.w - bf2f(h.w));
    hi[i] = h; lo[i] = l;
}

// ---------------- persistent 256x256 deep-pipelined GEMM -------------------
// Work = TILES x TOTKT kt-units, flattened tile-major and split into 256
// equal contiguous slices (one per block, 1 block/CU). Partial-tile results
// are atomicAdd'ed into zeroed outputs. f32-split bf16 folded as a single
// bf16 GEMM of K'=3K: A planes [Ah,Ah,Al], B planes [Bh,Bl,Bh].
// MODE 0: big projection. A=hs[1024xHID], B=W[NBIG x HID], out split xBC/zq.
// MODE 1: out GEMM. A=yg[1024xD_SSM], B=W_out[HID x D_SSM], out=[1024xHID].
//
// Replay-race hardening (vs failed v2):
//  * all gates are straight-line, compile-time gate_barrier<8/4/0> ladders
//    (no runtime-branched barrier selection);
//  * every segment ends with a FULL explicit vmcnt(0) drain after the atomic
//    flush, BEFORE __syncthreads. Rationale: the compiler need not drain
//    no-return global atomics at a workgroup barrier (they don't touch LDS),
//    so without this the next segment's counted gates would count leftover
//    atomics instead of stage loads -> stale-LDS compute. The explicit drain
//    restores the load-only in-order vmcnt regime (m135) for every gate.
template<int MODE>
__global__ __launch_bounds__(512, 2)
void gemm_persist(const ushort* __restrict__ Ah, const ushort* __restrict__ Al,
                  const ushort* __restrict__ Bh, const ushort* __restrict__ Bl,
                  float* __restrict__ O0, float* __restrict__ O1)
{
    constexpr int LDA   = (MODE == 0) ? HID : D_SSM;
    constexpr int LDB   = LDA;
    constexpr int TOTKT = (MODE == 0) ? 240 : 384;      // K'/32
    constexpr int KT3   = TOTKT / 3;                    // kt per K-third
    constexpr int UNITS = (MODE == 0) ? 196 * 240 : 40 * 384;
    constexpr int NROWB = (MODE == 0) ? NBIG : HID;     // valid B rows

    // 4 slots x {A,B} x 256 rows x 32 k (bf16) = 128 KiB
    __shared__ ushort lds[4][2][256][32];

    const int tid  = threadIdx.x;
    const int lane = tid & 63, wv = tid >> 6;

    // XCD-contiguous work id: blocks dispatch round-robin over 8 XCDs, so
    // give XCD x the contiguous work slices [32x, 32x+32).
    const int bid = blockIdx.x;
    const int wid = (bid & 7) * 32 + (bid >> 3);

    int u0 = (int)(((long)wid * UNITS) >> 8);           // /256 (256 blocks)
    const int u1 = (int)(((long)(wid + 1) * UNITS) >> 8);

    // stage-side lane mapping (linear LDS dest, pre-swizzled global source;
    // swizzle: phys_chunk = log_chunk ^ ((row>>1)&3))
    const int rb  = (wv << 4) + (lane >> 2);
    const int csw = (((lane & 3) ^ ((lane >> 3) & 3)) << 3);
    // compute-side: 8 waves as 2M x 4N, per-wave 128x64
    const int wm  = (wv >> 2) << 7;
    const int wn  = (wv & 3) << 6;
    const int fr  = lane & 15;
    const int ckr = (((lane >> 4) ^ ((lane >> 1) & 3)) << 3);
    const int rq  = (lane >> 4) << 2;

    while (u0 < u1) {
        const int tile = u0 / TOTKT;
        const int kt0  = u0 - tile * TOTKT;
        int nkt = TOTKT - kt0;
        if (nkt > u1 - u0) nkt = u1 - u0;

        const int m0 = (tile & 3) << 8;
        const int n0 = (tile >> 2) << 8;

        auto stage = [&](int kt, int slot) {
            int third = kt / KT3;
            int kk = (kt - third * KT3) * BKT;
            const ushort* Ap = (third == 2) ? Al : Ah;   // [Ah, Ah, Al]
            const ushort* Bp = (third == 1) ? Bl : Bh;   // [Bh, Bl, Bh]
            int cs = kk + csw;
            int ar0 = m0 + rb, ar1 = m0 + 128 + rb;
            int br0 = n0 + rb;       if (br0 > NROWB - 1) br0 = NROWB - 1;
            int br1 = n0 + 128 + rb; if (br1 > NROWB - 1) br1 = NROWB - 1;
            ushort* dA = &lds[slot][0][wv << 4][0];      // wave-uniform base
            ushort* dB = &lds[slot][1][wv << 4][0];
            async16(Ap + (size_t)ar0 * LDA + cs, dA);
            async16(Ap + (size_t)ar1 * LDA + cs, dA + 128 * 32);
            async16(Bp + (size_t)br0 * LDB + cs, dB);
            async16(Bp + (size_t)br1 * LDB + cs, dB + 128 * 32);
        };

        f32x4 acc[8][4];
        #pragma unroll
        for (int i = 0; i < 8; i++)
            #pragma unroll
            for (int j = 0; j < 4; j++) acc[i][j] = (f32x4){0.f, 0.f, 0.f, 0.f};

        auto compute = [&](int slot) {
            const ushort* sA = &lds[slot][0][0][0];
            const ushort* sB = &lds[slot][1][0][0];
            bf16x8 a[8], b[4];
            #pragma unroll
            for (int mt = 0; mt < 8; mt++)
                a[mt] = *(const bf16x8*)&sA[(wm + mt * 16 + fr) * 32 + ckr];
            #pragma unroll
            for (int nt = 0; nt < 4; nt++)
                b[nt] = *(const bf16x8*)&sB[(wn + nt * 16 + fr) * 32 + ckr];
            __builtin_amdgcn_s_setprio(1);
            #pragma unroll
            for (int mt = 0; mt < 8; mt++)
                #pragma unroll
                for (int nt = 0; nt < 4; nt++)
                    acc[mt][nt] = __builtin_amdgcn_mfma_f32_16x16x32_bf16(
                        a[mt], b[nt], acc[mt][nt], 0, 0, 0);
            __builtin_amdgcn_s_setprio(0);
        };

        if (nkt >= 4) {
            // prologue: prefetch depth 3 (12 loads/wave in flight)
            stage(kt0 + 0, 0); stage(kt0 + 1, 1); stage(kt0 + 2, 2);
            const int nsteady = nkt - 3;
            for (int i = 0; i < nsteady; i++) {
                gate_barrier<8>();                  // tile i lands (12 -> 8)
                stage(kt0 + i + 3, (i + 3) & 3);    // overwrite slot (i-1)&3
                compute(i & 3);
            }
            gate_barrier<8>(); compute((nkt - 3) & 3);   // 12 -> 8
            gate_barrier<4>(); compute((nkt - 2) & 3);   //  8 -> 4
            gate_barrier<0>(); compute((nkt - 1) & 3);   //  4 -> 0
        } else if (nkt == 3) {
            stage(kt0 + 0, 0); stage(kt0 + 1, 1); stage(kt0 + 2, 2);
            gate_barrier<8>(); compute(0);
            gate_barrier<4>(); compute(1);
            gate_barrier<0>(); compute(2);
        } else if (nkt == 2) {
            stage(kt0 + 0, 0); stage(kt0 + 1, 1);
            gate_barrier<4>(); compute(0);               //  8 -> 4
            gate_barrier<0>(); compute(1);
        } else {
            stage(kt0 + 0, 0);
            gate_barrier<0>(); compute(0);
        }

        // flush partial tile (outputs pre-zeroed; <=3 contributors/tile)
        #pragma unroll
        for (int mt = 0; mt < 8; mt++) {
            int row = m0 + wm + mt * 16 + rq;
            #pragma unroll
            for (int nt = 0; nt < 4; nt++) {
                int col = n0 + wn + nt * 16 + fr;
                if (MODE == 0) {
                    if (col < 8192) {
                        #pragma unroll
                        for (int r = 0; r < 4; r++)
                            atomicAdd(&O0[(size_t)(row + r) * 8192 + col],
                                      acc[mt][nt][r]);
                    } else if (col < NBIG) {
                        #pragma unroll
                        for (int r = 0; r < 4; r++)
                            atomicAdd(&O1[(size_t)(row + r) * NZ + (col - 8192)],
                                      acc[mt][nt][r]);
                    }
                } else {
                    #pragma unroll
                    for (int r = 0; r < 4; r++)
                        atomicAdd(&O0[(size_t)(row + r) * HID + col],
                                  acc[mt][nt][r]);
                }
            }
        }
        // HARD segment boundary: drain ALL vmem (incl. flush atomics) so the
        // next segment's counted gates see a load-only vmcnt stream.
        asm volatile("s_waitcnt vmcnt(0)" ::: "memory");
        __syncthreads();
        u0 += nkt;
    }
}

// ---------------- conv (K=4 causal) + SiLU ----------------
__global__ __launch_bounds__(256)
void conv_silu(const float* __restrict__ xBC, const float* __restrict__ conv_w,
               float* __restrict__ out) {
    int idx = blockIdx.x * 256 + threadIdx.x;
    if (idx >= LSEQ * D_INNER) return;
    int t = idx / D_INNER, c = idx - t * D_INNER;
    float acc = 0.f;
    #pragma unroll
    for (int k = 0; k < KCONV; k++) {
        int tt = t - (KCONV - 1) + k;
        if (tt >= 0) acc += xBC[(size_t)tt * D_INNER + c] * conv_w[c * KCONV + k];
    }
    out[idx] = siluf(acc);
}

// ---------------- S1: softplus(dt)+cumsum ----------------
__global__ __launch_bounds__(1024)
void dt_scan(const float* __restrict__ zq,
             const float* __restrict__ A_log, const float* __restrict__ dt_bias,
             float* __restrict__ dt_soft, float* __restrict__ Sbuf,
             float* __restrict__ Ebuf) {
    const int g = blockIdx.x, t = threadIdx.x;
    __shared__ float buf0[LSEQ], buf1[LSEQ];
    float dtr = zq[(size_t)t * NZ + D_SSM + g] + dt_bias[g];
    float dt = (dtr > 20.f) ? dtr : log1pf(expf(dtr));
    dt_soft[g * LSEQ + t] = dt;
    buf0[t] = dt;
    __syncthreads();
    float* src = buf0; float* dst = buf1;
    for (int off = 1; off < LSEQ; off <<= 1) {
        float v = src[t];
        if (t >= off) v += src[t - off];
        dst[t] = v;
        __syncthreads();
        float* tmp = src; src = dst; dst = tmp;
    }
    float A = -expf(A_log[g]);
    float S = A * src[t];
    Sbuf[g * LSEQ + t] = S;
    if ((t & (LC - 1)) == LC - 1) Ebuf[g * NC + (t >> 6)] = S;
}

// ---------------- S2: chunk states ----------------
__global__ __launch_bounds__(256)
void chunk_state(const float* __restrict__ xc, const float* __restrict__ dt_soft,
                 const float* __restrict__ Sbuf, const float* __restrict__ Ebuf,
                 float* __restrict__ Sc) {
    const int g = blockIdx.x, c = blockIdx.y;
    const int tid = threadIdx.x;
    const int t0 = c * LC;
    __shared__ __align__(16) float wB[LC][DS];
    __shared__ float Xs[LC][HD];
    __shared__ float sw[LC];

    if (tid < LC) {
        float Ec = Ebuf[g * NC + c];
        sw[tid] = expf(Ec - Sbuf[g * LSEQ + t0 + tid]) * dt_soft[g * LSEQ + t0 + tid];
    }
    __syncthreads();
    for (int i = tid; i < LC * DS; i += 256) {
        int r = i >> 6, s = i & 63;
        wB[r][s] = sw[r] * xc[(size_t)(t0 + r) * D_INNER + D_SSM + g * DS + s];
    }
    for (int i = tid; i < LC * HD; i += 256) {
        int r = i >> 7, h = i & 127;
        Xs[r][h] = xc[(size_t)(t0 + r) * D_INNER + g * HD + h];
    }
    __syncthreads();

    const int h = tid & 127, sh = (tid >> 7) * 32;
    float acc[32];
    #pragma unroll
    for (int j = 0; j < 32; j++) acc[j] = 0.f;
    for (int r = 0; r < LC; r++) {
        float xv = Xs[r][h];
        const float4* wrow = (const float4*)&wB[r][sh];
        #pragma unroll
        for (int q = 0; q < 8; q++) {
            float4 w4 = wrow[q];
            acc[4*q+0] += w4.x * xv;
            acc[4*q+1] += w4.y * xv;
            acc[4*q+2] += w4.z * xv;
            acc[4*q+3] += w4.w * xv;
        }
    }
    float* out = Sc + (size_t)(g * NC + c) * DS * HD;
    #pragma unroll
    for (int j = 0; j < 32; j++) out[(size_t)(sh + j) * HD + h] = acc[j];
}

// ---------------- S3: prefix over chunks ----------------
__global__ __launch_bounds__(256)
void chunk_prefix(const float* __restrict__ Sc, const float* __restrict__ Ebuf,
                  float* __restrict__ Hbuf) {
    const int g = blockIdx.y;
    const int e = blockIdx.x * 256 + threadIdx.x;
    float H = 0.f, Eprev = 0.f;
    for (int c = 0; c < NC; c++) {
        size_t base = (size_t)(g * NC + c) * DS * HD;
        Hbuf[base + e] = H;
        float Ec = Ebuf[g * NC + c];
        H = expf(Ec - Eprev) * H + Sc[base + e];
        Eprev = Ec;
    }
}

// ---------------- S4: per-chunk output + RMSNorm + SiLU(z), emits yg hi/lo ----
__global__ __launch_bounds__(256)
void chunk_output(const float* __restrict__ xc, const float* __restrict__ dt_soft,
                  const float* __restrict__ Sbuf, const float* __restrict__ Ebuf,
                  const float* __restrict__ Hbuf,
                  const float* __restrict__ zq, const float* __restrict__ norm_w,
                  ushort* __restrict__ ygH, ushort* __restrict__ ygL) {
    const int g = blockIdx.x, c = blockIdx.y;
    const int tid = threadIdx.x;
    const int t0 = c * LC;

    __shared__ __align__(16) float smem[4096 + 4096 + 8192];
    float* CT = smem;
    float* BW = smem + 4096;
    float* Xs = smem + 8192;
    float* red = smem;
    float* sscale = smem + 256;

    for (int i = tid; i < LC * DS; i += 256) {
        int t = i >> 6, s = i & 63;
        CT[s * LC + t] = xc[(size_t)(t0 + t) * D_INNER + D_SSM + NG * DS + g * DS + s];
        BW[t * DS + s] = xc[(size_t)(t0 + t) * D_INNER + D_SSM + g * DS + s];
    }
    for (int i = tid; i < LC * HD; i += 256) {
        int t = i >> 7, h = i & 127;
        Xs[t * HD + h] = xc[(size_t)(t0 + t) * D_INNER + g * HD + h];
    }
    __syncthreads();

    {
        const int t = tid & 63, tau0 = tid >> 6;
        float Greg[16];
        #pragma unroll
        for (int k = 0; k < 16; k++) Greg[k] = 0.f;
        for (int s = 0; s < DS; s++) {
            float cv = CT[s * LC + t];
            #pragma unroll
            for (int k = 0; k < 16; k++) Greg[k] += cv * BW[(tau0 + 4 * k) * DS + s];
        }
        __syncthreads();
        float St = Sbuf[g * LSEQ + t0 + t];
        #pragma unroll
        for (int k = 0; k < 16; k++) {
            int tau = tau0 + 4 * k;
            float w = 0.f;
            if (tau <= t)
                w = expf(St - Sbuf[g * LSEQ + t0 + tau]) *
                    dt_soft[g * LSEQ + t0 + tau] * Greg[k];
            BW[tau * LC + t] = w;
        }
    }
    __syncthreads();

    const int h = tid & 127, tb = (tid >> 7) * 32;
    float y[32], T[32];
    #pragma unroll
    for (int j = 0; j < 32; j++) { y[j] = 0.f; T[j] = 0.f; }

    for (int tau = 0; tau < LC; tau++) {
        float xv = Xs[tau * HD + h];
        const float4* wrow = (const float4*)&BW[tau * LC + tb];
        #pragma unroll
        for (int q = 0; q < 8; q++) {
            float4 w4 = wrow[q];
            y[4*q+0] += w4.x * xv;
            y[4*q+1] += w4.y * xv;
            y[4*q+2] += w4.z * xv;
            y[4*q+3] += w4.w * xv;
        }
    }
    {
        const float* Hg = Hbuf + (size_t)(g * NC + c) * DS * HD;
        for (int s = 0; s < DS; s++) {
            float Hv = Hg[(size_t)s * HD + h];
            const float* crow = &CT[s * LC + tb];
            #pragma unroll
            for (int j = 0; j < 32; j++) T[j] += crow[j] * Hv;
        }
    }
    float Eprev = (c > 0) ? Ebuf[g * NC + c - 1] : 0.f;
    #pragma unroll
    for (int j = 0; j < 32; j++) {
        int t = tb + j;
        float St = Sbuf[g * LSEQ + t0 + t];
        float Dv = zq[(size_t)(t0 + t) * NZ + D_SSM + NG + g];
        y[j] += expf(St - Eprev) * T[j] + Dv * Xs[t * HD + h];
    }
    __syncthreads();
    #pragma unroll
    for (int j = 0; j < 32; j++) Xs[(tb + j) * HD + h] = y[j];
    __syncthreads();

    {
        int t = tid >> 2, q = tid & 3;
        float p = 0.f;
        for (int i = 0; i < 32; i++) {
            float v = Xs[t * HD + q * 32 + i];
            p += v * v;
        }
        red[t * 4 + q] = p;
    }
    __syncthreads();
    if (tid < LC) {
        float s2 = red[tid*4] + red[tid*4+1] + red[tid*4+2] + red[tid*4+3];
        sscale[tid] = rsqrtf(s2 * (1.f / HD) + EPS_RMS);
    }
    __syncthreads();

    float nw = norm_w[h];
    #pragma unroll
    for (int j = 0; j < 32; j++) {
        int t = tb + j;
        float zv = zq[(size_t)(t0 + t) * NZ + g * HD + h];
        size_t idx = (size_t)(t0 + t) * D_SSM + g * HD + h;
        float val = y[j] * sscale[t] * nw * siluf(zv);
        unsigned short hb = f2bf(val);
        ygH[idx] = hb;
        ygL[idx] = f2bf(val - bf2f(hb));
    }
}

extern "C" void kernel_launch(void* const* d_in, const int* in_sizes, int n_in,
                              void* d_out, int out_size, void* d_ws, size_t ws_size,
                              hipStream_t stream) {
    const float* hs      = (const float*)d_in[0];
    const float* W_qkv   = (const float*)d_in[1];
    const float* W_z     = (const float*)d_in[2];
    const float* W_a     = (const float*)d_in[3];
    const float* W_b     = (const float*)d_in[4];
    const float* conv_w  = (const float*)d_in[5];
    const float* W_out   = (const float*)d_in[6];
    const float* norm_w  = (const float*)d_in[7];
    const float* A_log   = (const float*)d_in[8];
    const float* dt_bias = (const float*)d_in[9];
    float* out = (float*)d_out;

    float* ws      = (float*)d_ws;
    float* xBC     = ws;                                   // 8,388,608 f
    float* zq      = xBC + (size_t)LSEQ * D_INNER;         // 4,325,376 f
    float* dt_soft = zq + (size_t)LSEQ * NZ;               // 32768 f
    float* Sbuf    = dt_soft + (size_t)NG * LSEQ;          // 32768 f
    float* Ebuf    = Sbuf + (size_t)NG * LSEQ;             // 512 f
    ushort* hsH    = (ushort*)(Ebuf + 512);                // 2,621,440 us
    ushort* hsL    = hsH + (size_t)LSEQ * HID;
    ushort* WH     = hsL + (size_t)LSEQ * HID;             // NBIG*HID = 31,784,960 us
    ushort* WL     = WH + (size_t)NBIG * HID;
    // phase-2 overlay on WH/WL region (dead after gemm_persist<0>):
    float* xconv   = (float*)WH;                           // 8,388,608 f
    float* Sc      = xconv + (size_t)LSEQ * D_INNER;       // 4,194,304 f
    float* Hbuf    = Sc + (size_t)NG * NC * DS * HD;       // 4,194,304 f
    ushort* ygH    = (ushort*)(Hbuf + (size_t)NG * NC * DS * HD);  // 4,194,304 us
    ushort* ygL    = ygH + (size_t)LSEQ * D_SSM;
    ushort* WoH    = ygL + (size_t)LSEQ * D_SSM;           // 10,485,760 us
    ushort* WoL    = WoH + (size_t)HID * D_SSM;

    dim3 blk(256);

    // input/weight planes
    split_cvt<<<dim3((LSEQ * HID / 4 + 255) / 256), blk, 0, stream>>>(
        (const float4*)hs, (ushort4*)hsH, (ushort4*)hsL, LSEQ * HID / 4);
    split_cvt<<<dim3(((D_INNER * HID) / 4 + 255) / 256), blk, 0, stream>>>(
        (const float4*)W_qkv, (ushort4*)WH, (ushort4*)WL, (D_INNER * HID) / 4);
    split_cvt<<<dim3(((D_SSM * HID) / 4 + 255) / 256), blk, 0, stream>>>(
        (const float4*)W_z,
        (ushort4*)(WH + (size_t)D_INNER * HID), (ushort4*)(WL + (size_t)D_INNER * HID),
        (D_SSM * HID) / 4);
    split_cvt<<<dim3(((NG * HID) / 4 + 255) / 256), blk, 0, stream>>>(
        (const float4*)W_b,
        (ushort4*)(WH + (size_t)(D_INNER + D_SSM) * HID),
        (ushort4*)(WL + (size_t)(D_INNER + D_SSM) * HID), (NG * HID) / 4);
    split_cvt<<<dim3(((NG * HID) / 4 + 255) / 256), blk, 0, stream>>>(
        (const float4*)W_a,
        (ushort4*)(WH + (size_t)(D_INNER + D_SSM + NG) * HID),
        (ushort4*)(WL + (size_t)(D_INNER + D_SSM + NG) * HID), (NG * HID) / 4);

    // zero xBC+zq (contiguous) for persistent-GEMM atomic accumulation
    hipMemsetAsync(xBC, 0,
                   ((size_t)LSEQ * D_INNER + (size_t)LSEQ * NZ) * sizeof(float),
                   stream);

    // persistent projection GEMM: 256 blocks, balanced (tile,kt) slices
    gemm_persist<0><<<dim3(256), dim3(512), 0, stream>>>(
        hsH, hsL, WH, WL, xBC, zq);

    conv_silu<<<dim3((LSEQ * D_INNER) / 256), blk, 0, stream>>>(xBC, conv_w, xconv);

    dt_scan<<<dim3(NG), dim3(1024), 0, stream>>>(zq, A_log, dt_bias,
                                                 dt_soft, Sbuf, Ebuf);
    chunk_state<<<dim3(NG, NC), blk, 0, stream>>>(xconv, dt_soft, Sbuf, Ebuf, Sc);
    chunk_prefix<<<dim3(DS * HD / 256, NG), blk, 0, stream>>>(Sc, Ebuf, Hbuf);
    chunk_output<<<dim3(NG, NC), blk, 0, stream>>>(xconv, dt_soft, Sbuf, Ebuf,
                                                   Hbuf, zq, norm_w, ygH, ygL);

    // out = yg @ W_out^T via the same persistent template (40 tiles x 384 kt)
    split_cvt<<<dim3(((HID * D_SSM) / 4 + 255) / 256), blk, 0, stream>>>(
        (const float4*)W_out, (ushort4*)WoH, (ushort4*)WoL, (HID * D_SSM) / 4);
    hipMemsetAsync(out, 0, (size_t)LSEQ * HID * sizeof(float), stream);
    gemm_persist<1><<<dim3(256), dim3(512), 0, stream>>>(
        ygH, ygL, WoH, WoL, out, nullptr);
}

// Round 7
// 641.743 us; speedup vs baseline: 1.1184x; 1.1184x over previous
//
#include <hip/hip_runtime.h>
#include <hip/hip_bf16.h>
#include <math.h>

#define HID     2560
#define D_INNER 8192
#define NG      32
#define D_SSM   4096
#define KCONV   4
#define HD      128
#define DS      64
#define LSEQ    1024
#define LC      64
#define NC      (LSEQ / LC)
#define NZ      4224          // z(4096) + dt(32) + D(32) + pad(64)
#define NBIG    12416         // qkv(8192) + NZ
#define EPS_RMS 1e-6f

// ---- gemm_big256 deep-pipeline params ----
#define BKT       32          // K per tile (one 16x16x32 MFMA k-depth)
#define NKT       240         // K' = 3*2560 -> 240 tiles of 32
#define GB_BLOCKS 196         // 49 n-tiles * 4 m-tiles

typedef short bf16x8 __attribute__((ext_vector_type(8)));
typedef float f32x4 __attribute__((ext_vector_type(4)));

__device__ __forceinline__ float siluf(float x) { return x / (1.f + expf(-x)); }

__device__ __forceinline__ unsigned short f2bf(float x) {
    __hip_bfloat16 b = __float2bfloat16(x);
    return *reinterpret_cast<unsigned short*>(&b);
}
__device__ __forceinline__ float bf2f(unsigned short u) {
    union { unsigned int i; float f; } v;
    v.i = ((unsigned int)u) << 16;
    return v.f;
}

__device__ __forceinline__ void async16(const ushort* g, ushort* l) {
    __builtin_amdgcn_global_load_lds(
        (const __attribute__((address_space(1))) unsigned int*)g,
        (__attribute__((address_space(3))) unsigned int*)l, 16, 0, 0);
}

// counted-vmcnt gate: drain own ds_reads (lgkmcnt 0), leave VM staging loads
// in flight across the raw barrier (T4). Compile-time VM only.
template<int VM>
__device__ __forceinline__ void gate_barrier() {
    asm volatile("s_waitcnt vmcnt(%0) lgkmcnt(0)" :: "n"(VM) : "memory");
    __builtin_amdgcn_s_barrier();
    asm volatile("" ::: "memory");
}

// ---------------- f32 -> (hi, lo) bf16 planes ----------------
__global__ __launch_bounds__(256)
void split_cvt(const float4* __restrict__ in, ushort4* __restrict__ hi,
               ushort4* __restrict__ lo, int n4) {
    int i = blockIdx.x * 256 + threadIdx.x;
    if (i >= n4) return;
    float4 v = in[i];
    ushort4 h, l;
    h.x = f2bf(v.x); l.x = f2bf(v.x - bf2f(h.x));
    h.y = f2bf(v.y); l.y = f2bf(v.y - bf2f(h.y));
    h.z = f2bf(v.z); l.z = f2bf(v.z - bf2f(h.z));
    h.w = f2bf(v.w); l.w = f2bf(v.w - bf2f(h.w));
    hi[i] = h; lo[i] = l;
}

// ---------------- big GEMM, 256x256 tile, 4-slot ring, counted vmcnt --------
// ROUND-1 PROVEN FORM (208.8 us, FETCH ~160MB, bank conflicts 0). 196 blocks,
// one full-K tile per block, direct stores. Panel-major XCD swizzle keeps the
// 4 m-tiles of each n-panel concurrent on one XCD -> B weights fetched ~once.
// NOTE: do NOT fold other work into spare blocks of this kernel — every large
// workspace region (WH/WL overlay included) is live-read here (round-6 bug).
__global__ __launch_bounds__(512, 2)
void gemm_big256(const ushort* __restrict__ Ah, const ushort* __restrict__ Al,
                 const ushort* __restrict__ Bh, const ushort* __restrict__ Bl,
                 float* __restrict__ xBC, float* __restrict__ zq)
{
    // 4 slots x {A,B} x 256 rows x 32 k-elems (bf16) = 128 KiB
    __shared__ ushort lds[4][2][256][32];

    const int tid  = threadIdx.x;
    const int lane = tid & 63, wv = tid >> 6;

    // bijective XCD swizzle (m204) then panel-major decompose.
    int id = blockIdx.x;
    const int qx = GB_BLOCKS / 8, rx = GB_BLOCKS % 8;       // 24, 4
    int xcd = id & 7, lid = id >> 3;
    int sw  = (xcd < rx) ? (xcd * (qx + 1) + lid)
                         : (rx * (qx + 1) + (xcd - rx) * qx + lid);
    const int m0 = (sw & 3) << 8;       // 0..768
    const int n0 = (sw >> 2) << 8;      // 0..12288

    // stage-side lane mapping (linear LDS dest, pre-swizzled global source;
    // swizzle: phys_chunk = log_chunk ^ ((row>>1)&3))
    const int rb  = (wv << 4) + (lane >> 2);                    // row in 128-half
    const int csw = (((lane & 3) ^ ((lane >> 3) & 3)) << 3);    // source k-chunk

    auto stage = [&](int kt, int slot) {
        int third = kt / 80;                    // 80 tiles per K-third
        int kk = (kt - third * 80) * BKT;
        const ushort* Ap = (third == 2) ? Al : Ah;   // [Ah, Ah, Al]
        const ushort* Bp = (third == 1) ? Bl : Bh;   // [Bh, Bl, Bh]
        int cs = kk + csw;
        int ar0 = m0 + rb, ar1 = m0 + 128 + rb;
        int br0 = n0 + rb;        if (br0 > NBIG - 1) br0 = NBIG - 1;  // pad clamp
        int br1 = n0 + 128 + rb;  if (br1 > NBIG - 1) br1 = NBIG - 1;
        ushort* dA = &lds[slot][0][wv << 4][0];      // wave-uniform base
        ushort* dB = &lds[slot][1][wv << 4][0];
        async16(Ap + (size_t)ar0 * HID + cs, dA);
        async16(Ap + (size_t)ar1 * HID + cs, dA + 128 * 32);
        async16(Bp + (size_t)br0 * HID + cs, dB);
        async16(Bp + (size_t)br1 * HID + cs, dB + 128 * 32);
    };

    // compute-side: 8 waves as 2M x 4N, per-wave 128x64
    const int wm  = (wv >> 2) << 7;                 // 0 / 128
    const int wn  = (wv & 3) << 6;                  // 0 / 64 / 128 / 192
    const int fr  = lane & 15;
    const int ckr = ((((lane >> 4) ^ ((lane >> 1) & 3))) << 3);  // swizzled read chunk

    f32x4 acc[8][4];
    #pragma unroll
    for (int i = 0; i < 8; i++)
        #pragma unroll
        for (int j = 0; j < 4; j++) acc[i][j] = (f32x4){0.f, 0.f, 0.f, 0.f};

    auto compute = [&](int slot) {
        const ushort* sA = &lds[slot][0][0][0];
        const ushort* sB = &lds[slot][1][0][0];
        bf16x8 a[8], b[4];
        #pragma unroll
        for (int mt = 0; mt < 8; mt++)
            a[mt] = *(const bf16x8*)&sA[(wm + mt * 16 + fr) * 32 + ckr];
        #pragma unroll
        for (int nt = 0; nt < 4; nt++)
            b[nt] = *(const bf16x8*)&sB[(wn + nt * 16 + fr) * 32 + ckr];
        __builtin_amdgcn_s_setprio(1);
        #pragma unroll
        for (int mt = 0; mt < 8; mt++)
            #pragma unroll
            for (int nt = 0; nt < 4; nt++)
                acc[mt][nt] = __builtin_amdgcn_mfma_f32_16x16x32_bf16(
                    a[mt], b[nt], acc[mt][nt], 0, 0, 0);
        __builtin_amdgcn_s_setprio(0);
    };

    // prologue: fill prefetch depth 3 (12 loads/wave in flight)
    stage(0, 0); stage(1, 1); stage(2, 2);

    #pragma unroll 4
    for (int kt = 0; kt < NKT - 4; kt++) {          // 0..235
        gate_barrier<8>();
        stage(kt + 3, (kt + 3) & 3);
        compute(kt & 3);
    }
    gate_barrier<8>(); stage(239, 3); compute(0);   // kt = 236
    gate_barrier<8>(); compute(1);                  // kt = 237
    gate_barrier<4>(); compute(2);                  // kt = 238
    gate_barrier<0>(); compute(3);                  // kt = 239

    // ---- epilogue: C[row][col], col split xBC/zq, pad cols dropped ----
    const int rq = (lane >> 4) << 2;
    #pragma unroll
    for (int mt = 0; mt < 8; mt++) {
        int row = m0 + wm + mt * 16 + rq;
        #pragma unroll
        for (int nt = 0; nt < 4; nt++) {
            int col = n0 + wn + nt * 16 + fr;
            if (col < 8192) {
                #pragma unroll
                for (int r = 0; r < 4; r++)
                    xBC[(size_t)(row + r) * 8192 + col] = acc[mt][nt][r];
            } else if (col < NBIG) {
                #pragma unroll
                for (int r = 0; r < 4; r++)
                    zq[(size_t)(row + r) * NZ + (col - 8192)] = acc[mt][nt][r];
            }
        }
    }
}

// ---------------- out GEMM: 256^2 tiles, split-K x6, 240 blocks -------------
// out[1024,2560] = yg[1024,4096] @ W_out[2560,4096]^T, f32-split folded as
// K'=3K=12288 -> 384 kt. Exact decomposition: 4 m x 10 n x 6 kz (64 kt each,
// each kz within one plane-third). All 240 jobs co-resident; the 4 m-tiles
// sharing a (n,kz) B-slab are adjacent wids -> same XCD -> concurrent L2 hit.
// Single atomic flush per block into memset-zeroed out.
__global__ __launch_bounds__(512, 2)
void gemm_out_sk256(const ushort* __restrict__ Ah, const ushort* __restrict__ Al,
                    const ushort* __restrict__ Bh, const ushort* __restrict__ Bl,
                    float* __restrict__ C)
{
    constexpr int LDA = D_SSM;          // 4096 (A and B leading dim)
    constexpr int KT3 = 128;            // kt per K-third

    __shared__ ushort lds[4][2][256][32];

    const int tid  = threadIdx.x;
    const int lane = tid & 63, wv = tid >> 6;

    // XCD-contiguous wid: 240 = 8 XCDs x 30 blocks
    const int bid = blockIdx.x;
    const int wid = (bid & 7) * 30 + (bid >> 3);
    const int m   = wid & 3;
    const int q   = wid >> 2;           // 0..59
    const int n   = q % 10;
    const int kz  = q / 10;             // 0..5
    const int m0  = m << 8, n0 = n << 8;
    const int kt0 = kz * 64;            // 64-kt slice, within one plane-third

    const int rb  = (wv << 4) + (lane >> 2);
    const int csw = (((lane & 3) ^ ((lane >> 3) & 3)) << 3);
    const int wm  = (wv >> 2) << 7;
    const int wn  = (wv & 3) << 6;
    const int fr  = lane & 15;
    const int ckr = (((lane >> 4) ^ ((lane >> 1) & 3)) << 3);
    const int rq  = (lane >> 4) << 2;

    auto stage = [&](int kt, int slot) {
        int third = kt / KT3;
        int kk = (kt - third * KT3) * BKT;
        const ushort* Ap = (third == 2) ? Al : Ah;   // [Ah, Ah, Al]
        const ushort* Bp = (third == 1) ? Bl : Bh;   // [Bh, Bl, Bh]
        int cs = kk + csw;
        ushort* dA = &lds[slot][0][wv << 4][0];
        ushort* dB = &lds[slot][1][wv << 4][0];
        async16(Ap + (size_t)(m0 + rb) * LDA + cs, dA);
        async16(Ap + (size_t)(m0 + 128 + rb) * LDA + cs, dA + 128 * 32);
        async16(Bp + (size_t)(n0 + rb) * LDA + cs, dB);
        async16(Bp + (size_t)(n0 + 128 + rb) * LDA + cs, dB + 128 * 32);
    };

    f32x4 acc[8][4];
    #pragma unroll
    for (int i = 0; i < 8; i++)
        #pragma unroll
        for (int j = 0; j < 4; j++) acc[i][j] = (f32x4){0.f, 0.f, 0.f, 0.f};

    auto compute = [&](int slot) {
        const ushort* sA = &lds[slot][0][0][0];
        const ushort* sB = &lds[slot][1][0][0];
        bf16x8 a[8], b[4];
        #pragma unroll
        for (int mt = 0; mt < 8; mt++)
            a[mt] = *(const bf16x8*)&sA[(wm + mt * 16 + fr) * 32 + ckr];
        #pragma unroll
        for (int nt = 0; nt < 4; nt++)
            b[nt] = *(const bf16x8*)&sB[(wn + nt * 16 + fr) * 32 + ckr];
        __builtin_amdgcn_s_setprio(1);
        #pragma unroll
        for (int mt = 0; mt < 8; mt++)
            #pragma unroll
            for (int nt = 0; nt < 4; nt++)
                acc[mt][nt] = __builtin_amdgcn_mfma_f32_16x16x32_bf16(
                    a[mt], b[nt], acc[mt][nt], 0, 0, 0);
        __builtin_amdgcn_s_setprio(0);
    };

    // straight-line 64-kt pipeline (proven gate ladder)
    stage(kt0 + 0, 0); stage(kt0 + 1, 1); stage(kt0 + 2, 2);
    #pragma unroll 4
    for (int i = 0; i < 60; i++) {
        gate_barrier<8>();
        stage(kt0 + i + 3, (i + 3) & 3);
        compute(i & 3);
    }
    gate_barrier<8>(); stage(kt0 + 63, 63 & 3); compute(60 & 3);
    gate_barrier<8>(); compute(61 & 3);
    gate_barrier<4>(); compute(62 & 3);
    gate_barrier<0>(); compute(63 & 3);

    // flush (out pre-zeroed; 6 contributors per element)
    #pragma unroll
    for (int mt = 0; mt < 8; mt++) {
        int row = m0 + wm + mt * 16 + rq;
        #pragma unroll
        for (int nt = 0; nt < 4; nt++) {
            int col = n0 + wn + nt * 16 + fr;
            #pragma unroll
            for (int r = 0; r < 4; r++)
                atomicAdd(&C[(size_t)(row + r) * HID + col], acc[mt][nt][r]);
        }
    }
}

// ---------------- conv (K=4 causal) + SiLU ----------------
__global__ __launch_bounds__(256)
void conv_silu(const float* __restrict__ xBC, const float* __restrict__ conv_w,
               float* __restrict__ out) {
    int idx = blockIdx.x * 256 + threadIdx.x;
    if (idx >= LSEQ * D_INNER) return;
    int t = idx / D_INNER, c = idx - t * D_INNER;
    float acc = 0.f;
    #pragma unroll
    for (int k = 0; k < KCONV; k++) {
        int tt = t - (KCONV - 1) + k;
        if (tt >= 0) acc += xBC[(size_t)tt * D_INNER + c] * conv_w[c * KCONV + k];
    }
    out[idx] = siluf(acc);
}

// ---------------- S1: softplus(dt)+cumsum ----------------
__global__ __launch_bounds__(1024)
void dt_scan(const float* __restrict__ zq,
             const float* __restrict__ A_log, const float* __restrict__ dt_bias,
             float* __restrict__ dt_soft, float* __restrict__ Sbuf,
             float* __restrict__ Ebuf) {
    const int g = blockIdx.x, t = threadIdx.x;
    __shared__ float buf0[LSEQ], buf1[LSEQ];
    float dtr = zq[(size_t)t * NZ + D_SSM + g] + dt_bias[g];
    float dt = (dtr > 20.f) ? dtr : log1pf(expf(dtr));
    dt_soft[g * LSEQ + t] = dt;
    buf0[t] = dt;
    __syncthreads();
    float* src = buf0; float* dst = buf1;
    for (int off = 1; off < LSEQ; off <<= 1) {
        float v = src[t];
        if (t >= off) v += src[t - off];
        dst[t] = v;
        __syncthreads();
        float* tmp = src; src = dst; dst = tmp;
    }
    float A = -expf(A_log[g]);
    float S = A * src[t];
    Sbuf[g * LSEQ + t] = S;
    if ((t & (LC - 1)) == LC - 1) Ebuf[g * NC + (t >> 6)] = S;
}

// ---------------- S2: chunk states ----------------
__global__ __launch_bounds__(256)
void chunk_state(const float* __restrict__ xc, const float* __restrict__ dt_soft,
                 const float* __restrict__ Sbuf, const float* __restrict__ Ebuf,
                 float* __restrict__ Sc) {
    const int g = blockIdx.x, c = blockIdx.y;
    const int tid = threadIdx.x;
    const int t0 = c * LC;
    __shared__ __align__(16) float wB[LC][DS];
    __shared__ float Xs[LC][HD];
    __shared__ float sw[LC];

    if (tid < LC) {
        float Ec = Ebuf[g * NC + c];
        sw[tid] = expf(Ec - Sbuf[g * LSEQ + t0 + tid]) * dt_soft[g * LSEQ + t0 + tid];
    }
    __syncthreads();
    for (int i = tid; i < LC * DS; i += 256) {
        int r = i >> 6, s = i & 63;
        wB[r][s] = sw[r] * xc[(size_t)(t0 + r) * D_INNER + D_SSM + g * DS + s];
    }
    for (int i = tid; i < LC * HD; i += 256) {
        int r = i >> 7, h = i & 127;
        Xs[r][h] = xc[(size_t)(t0 + r) * D_INNER + g * HD + h];
    }
    __syncthreads();

    const int h = tid & 127, sh = (tid >> 7) * 32;
    float acc[32];
    #pragma unroll
    for (int j = 0; j < 32; j++) acc[j] = 0.f;
    for (int r = 0; r < LC; r++) {
        float xv = Xs[r][h];
        const float4* wrow = (const float4*)&wB[r][sh];
        #pragma unroll
        for (int q = 0; q < 8; q++) {
            float4 w4 = wrow[q];
            acc[4*q+0] += w4.x * xv;
            acc[4*q+1] += w4.y * xv;
            acc[4*q+2] += w4.z * xv;
            acc[4*q+3] += w4.w * xv;
        }
    }
    float* out = Sc + (size_t)(g * NC + c) * DS * HD;
    #pragma unroll
    for (int j = 0; j < 32; j++) out[(size_t)(sh + j) * HD + h] = acc[j];
}

// ---------------- S3: prefix over chunks ----------------
__global__ __launch_bounds__(256)
void chunk_prefix(const float* __restrict__ Sc, const float* __restrict__ Ebuf,
                  float* __restrict__ Hbuf) {
    const int g = blockIdx.y;
    const int e = blockIdx.x * 256 + threadIdx.x;
    float H = 0.f, Eprev = 0.f;
    for (int c = 0; c < NC; c++) {
        size_t base = (size_t)(g * NC + c) * DS * HD;
        Hbuf[base + e] = H;
        float Ec = Ebuf[g * NC + c];
        H = expf(Ec - Eprev) * H + Sc[base + e];
        Eprev = Ec;
    }
}

// ---------------- S4: per-chunk output + RMSNorm + SiLU(z), emits yg hi/lo ----
__global__ __launch_bounds__(256)
void chunk_output(const float* __restrict__ xc, const float* __restrict__ dt_soft,
                  const float* __restrict__ Sbuf, const float* __restrict__ Ebuf,
                  const float* __restrict__ Hbuf,
                  const float* __restrict__ zq, const float* __restrict__ norm_w,
                  ushort* __restrict__ ygH, ushort* __restrict__ ygL) {
    const int g = blockIdx.x, c = blockIdx.y;
    const int tid = threadIdx.x;
    const int t0 = c * LC;

    __shared__ __align__(16) float smem[4096 + 4096 + 8192];
    float* CT = smem;
    float* BW = smem + 4096;
    float* Xs = smem + 8192;
    float* red = smem;
    float* sscale = smem + 256;

    for (int i = tid; i < LC * DS; i += 256) {
        int t = i >> 6, s = i & 63;
        CT[s * LC + t] = xc[(size_t)(t0 + t) * D_INNER + D_SSM + NG * DS + g * DS + s];
        BW[t * DS + s] = xc[(size_t)(t0 + t) * D_INNER + D_SSM + g * DS + s];
    }
    for (int i = tid; i < LC * HD; i += 256) {
        int t = i >> 7, h = i & 127;
        Xs[t * HD + h] = xc[(size_t)(t0 + t) * D_INNER + g * HD + h];
    }
    __syncthreads();

    {
        const int t = tid & 63, tau0 = tid >> 6;
        float Greg[16];
        #pragma unroll
        for (int k = 0; k < 16; k++) Greg[k] = 0.f;
        for (int s = 0; s < DS; s++) {
            float cv = CT[s * LC + t];
            #pragma unroll
            for (int k = 0; k < 16; k++) Greg[k] += cv * BW[(tau0 + 4 * k) * DS + s];
        }
        __syncthreads();
        float St = Sbuf[g * LSEQ + t0 + t];
        #pragma unroll
        for (int k = 0; k < 16; k++) {
            int tau = tau0 + 4 * k;
            float w = 0.f;
            if (tau <= t)
                w = expf(St - Sbuf[g * LSEQ + t0 + tau]) *
                    dt_soft[g * LSEQ + t0 + tau] * Greg[k];
            BW[tau * LC + t] = w;
        }
    }
    __syncthreads();

    const int h = tid & 127, tb = (tid >> 7) * 32;
    float y[32], T[32];
    #pragma unroll
    for (int j = 0; j < 32; j++) { y[j] = 0.f; T[j] = 0.f; }

    for (int tau = 0; tau < LC; tau++) {
        float xv = Xs[tau * HD + h];
        const float4* wrow = (const float4*)&BW[tau * LC + tb];
        #pragma unroll
        for (int q = 0; q < 8; q++) {
            float4 w4 = wrow[q];
            y[4*q+0] += w4.x * xv;
            y[4*q+1] += w4.y * xv;
            y[4*q+2] += w4.z * xv;
            y[4*q+3] += w4.w * xv;
        }
    }
    {
        const float* Hg = Hbuf + (size_t)(g * NC + c) * DS * HD;
        for (int s = 0; s < DS; s++) {
            float Hv = Hg[(size_t)s * HD + h];
            const float* crow = &CT[s * LC + tb];
            #pragma unroll
            for (int j = 0; j < 32; j++) T[j] += crow[j] * Hv;
        }
    }
    float Eprev = (c > 0) ? Ebuf[g * NC + c - 1] : 0.f;
    #pragma unroll
    for (int j = 0; j < 32; j++) {
        int t = tb + j;
        float St = Sbuf[g * LSEQ + t0 + t];
        float Dv = zq[(size_t)(t0 + t) * NZ + D_SSM + NG + g];
        y[j] += expf(St - Eprev) * T[j] + Dv * Xs[t * HD + h];
    }
    __syncthreads();
    #pragma unroll
    for (int j = 0; j < 32; j++) Xs[(tb + j) * HD + h] = y[j];
    __syncthreads();

    {
        int t = tid >> 2, q = tid & 3;
        float p = 0.f;
        for (int i = 0; i < 32; i++) {
            float v = Xs[t * HD + q * 32 + i];
            p += v * v;
        }
        red[t * 4 + q] = p;
    }
    __syncthreads();
    if (tid < LC) {
        float s2 = red[tid*4] + red[tid*4+1] + red[tid*4+2] + red[tid*4+3];
        sscale[tid] = rsqrtf(s2 * (1.f / HD) + EPS_RMS);
    }
    __syncthreads();

    float nw = norm_w[h];
    #pragma unroll
    for (int j = 0; j < 32; j++) {
        int t = tb + j;
        float zv = zq[(size_t)(t0 + t) * NZ + g * HD + h];
        size_t idx = (size_t)(t0 + t) * D_SSM + g * HD + h;
        float val = y[j] * sscale[t] * nw * siluf(zv);
        unsigned short hb = f2bf(val);
        ygH[idx] = hb;
        ygL[idx] = f2bf(val - bf2f(hb));
    }
}

extern "C" void kernel_launch(void* const* d_in, const int* in_sizes, int n_in,
                              void* d_out, int out_size, void* d_ws, size_t ws_size,
                              hipStream_t stream) {
    const float* hs      = (const float*)d_in[0];
    const float* W_qkv   = (const float*)d_in[1];
    const float* W_z     = (const float*)d_in[2];
    const float* W_a     = (const float*)d_in[3];
    const float* W_b     = (const float*)d_in[4];
    const float* conv_w  = (const float*)d_in[5];
    const float* W_out   = (const float*)d_in[6];
    const float* norm_w  = (const float*)d_in[7];
    const float* A_log   = (const float*)d_in[8];
    const float* dt_bias = (const float*)d_in[9];
    float* out = (float*)d_out;

    float* ws      = (float*)d_ws;
    float* xBC     = ws;                                   // 8,388,608 f
    float* zq      = xBC + (size_t)LSEQ * D_INNER;         // 4,325,376 f
    float* dt_soft = zq + (size_t)LSEQ * NZ;               // 32768 f
    float* Sbuf    = dt_soft + (size_t)NG * LSEQ;          // 32768 f
    float* Ebuf    = Sbuf + (size_t)NG * LSEQ;             // 512 f
    ushort* hsH    = (ushort*)(Ebuf + 512);                // 2,621,440 us
    ushort* hsL    = hsH + (size_t)LSEQ * HID;
    ushort* WH     = hsL + (size_t)LSEQ * HID;             // NBIG*HID = 31,784,960 us
    ushort* WL     = WH + (size_t)NBIG * HID;
    // phase-2 overlay on WH/WL region (dead after gemm_big256):
    float* xconv   = (float*)WH;                           // 8,388,608 f
    float* Sc      = xconv + (size_t)LSEQ * D_INNER;       // 4,194,304 f
    float* Hbuf    = Sc + (size_t)NG * NC * DS * HD;       // 4,194,304 f
    ushort* ygH    = (ushort*)(Hbuf + (size_t)NG * NC * DS * HD);  // 4,194,304 us
    ushort* ygL    = ygH + (size_t)LSEQ * D_SSM;
    ushort* WoH    = ygL + (size_t)LSEQ * D_SSM;           // 10,485,760 us
    ushort* WoL    = WoH + (size_t)HID * D_SSM;

    dim3 blk(256);

    // input/weight planes
    split_cvt<<<dim3((LSEQ * HID / 4 + 255) / 256), blk, 0, stream>>>(
        (const float4*)hs, (ushort4*)hsH, (ushort4*)hsL, LSEQ * HID / 4);
    split_cvt<<<dim3(((D_INNER * HID) / 4 + 255) / 256), blk, 0, stream>>>(
        (const float4*)W_qkv, (ushort4*)WH, (ushort4*)WL, (D_INNER * HID) / 4);
    split_cvt<<<dim3(((D_SSM * HID) / 4 + 255) / 256), blk, 0, stream>>>(
        (const float4*)W_z,
        (ushort4*)(WH + (size_t)D_INNER * HID), (ushort4*)(WL + (size_t)D_INNER * HID),
        (D_SSM * HID) / 4);
    split_cvt<<<dim3(((NG * HID) / 4 + 255) / 256), blk, 0, stream>>>(
        (const float4*)W_b,
        (ushort4*)(WH + (size_t)(D_INNER + D_SSM) * HID),
        (ushort4*)(WL + (size_t)(D_INNER + D_SSM) * HID), (NG * HID) / 4);
    split_cvt<<<dim3(((NG * HID) / 4 + 255) / 256), blk, 0, stream>>>(
        (const float4*)W_a,
        (ushort4*)(WH + (size_t)(D_INNER + D_SSM + NG) * HID),
        (ushort4*)(WL + (size_t)(D_INNER + D_SSM + NG) * HID), (NG * HID) / 4);

    // merged projection GEMM: 196 blocks, proven round-1 form
    gemm_big256<<<dim3(GB_BLOCKS), dim3(512), 0, stream>>>(
        hsH, hsL, WH, WL, xBC, zq);

    // W_out planes — AFTER gemm_big256 (WoH/WoL alias the WL region, which is
    // live-read during the GEMM; round-6 lesson).
    split_cvt<<<dim3(((HID * D_SSM) / 4 + 255) / 256), blk, 0, stream>>>(
        (const float4*)W_out, (ushort4*)WoH, (ushort4*)WoL, (HID * D_SSM) / 4);

    conv_silu<<<dim3((LSEQ * D_INNER) / 256), blk, 0, stream>>>(xBC, conv_w, xconv);

    dt_scan<<<dim3(NG), dim3(1024), 0, stream>>>(zq, A_log, dt_bias,
                                                 dt_soft, Sbuf, Ebuf);
    chunk_state<<<dim3(NG, NC), blk, 0, stream>>>(xconv, dt_soft, Sbuf, Ebuf, Sc);
    chunk_prefix<<<dim3(DS * HD / 256, NG), blk, 0, stream>>>(Sc, Ebuf, Hbuf);
    chunk_output<<<dim3(NG, NC), blk, 0, stream>>>(xconv, dt_soft, Sbuf, Ebuf,
                                                   Hbuf, zq, norm_w, ygH, ygL);

    // out = yg @ W_out^T: 240-block 256^2 split-K x6, atomic accumulate
    hipMemsetAsync(out, 0, (size_t)LSEQ * HID * sizeof(float), stream);
    gemm_out_sk256<<<dim3(240), dim3(512), 0, stream>>>(
        ygH, ygL, WoH, WoL, out);
}

// Round 8
// 612.202 us; speedup vs baseline: 1.1723x; 1.0483x over previous
//
#include <hip/hip_runtime.h>
#include <hip/hip_bf16.h>
#include <math.h>

#define HID     2560
#define D_INNER 8192
#define NG      32
#define D_SSM   4096
#define KCONV   4
#define HD      128
#define DS      64
#define LSEQ    1024
#define LC      64
#define NC      (LSEQ / LC)
#define NZ      4224          // z(4096) + dt(32) + D(32) + pad(64)
#define NBIG    12416         // qkv(8192) + NZ
#define EPS_RMS 1e-6f

// ---- gemm_big256 deep-pipeline params ----
#define BKT       32          // K per tile (one 16x16x32 MFMA k-depth)
#define NKT       240         // K' = 3*2560 -> 240 tiles of 32
#define GB_BLOCKS 196         // 49 n-tiles * 4 m-tiles

typedef short bf16x8 __attribute__((ext_vector_type(8)));
typedef float f32x4 __attribute__((ext_vector_type(4)));

__device__ __forceinline__ float siluf(float x) { return x / (1.f + expf(-x)); }

__device__ __forceinline__ unsigned short f2bf(float x) {
    __hip_bfloat16 b = __float2bfloat16(x);
    return *reinterpret_cast<unsigned short*>(&b);
}
__device__ __forceinline__ float bf2f(unsigned short u) {
    union { unsigned int i; float f; } v;
    v.i = ((unsigned int)u) << 16;
    return v.f;
}

__device__ __forceinline__ void async16(const ushort* g, ushort* l) {
    __builtin_amdgcn_global_load_lds(
        (const __attribute__((address_space(1))) unsigned int*)g,
        (__attribute__((address_space(3))) unsigned int*)l, 16, 0, 0);
}

// counted-vmcnt gate: drain own ds_reads (lgkmcnt 0), leave VM staging loads
// in flight across the raw barrier (T4). Compile-time VM only.
template<int VM>
__device__ __forceinline__ void gate_barrier() {
    asm volatile("s_waitcnt vmcnt(%0) lgkmcnt(0)" :: "n"(VM) : "memory");
    __builtin_amdgcn_s_barrier();
    asm volatile("" ::: "memory");
}

__device__ __forceinline__ void cvt4(const float4& v, ushort4& h, ushort4& l) {
    h.x = f2bf(v.x); l.x = f2bf(v.x - bf2f(h.x));
    h.y = f2bf(v.y); l.y = f2bf(v.y - bf2f(h.y));
    h.z = f2bf(v.z); l.z = f2bf(v.z - bf2f(h.z));
    h.w = f2bf(v.w); l.w = f2bf(v.w - bf2f(h.w));
}

// ---------------- fused input-plane conversion (5 launches -> 1) -----------
// Segments (float4 units): hs 655360 | W_qkv 5242880 | W_z 2621440 |
// W_b 20480 | W_a 20480.  Total 8,560,640 = 33440 blocks x 256.
#define N4_HS   (LSEQ * HID / 4)
#define N4_QKV  (D_INNER * HID / 4)
#define N4_Z    (D_SSM * HID / 4)
#define N4_BA   (NG * HID / 4)
__global__ __launch_bounds__(256)
void split_cvt_all(const float4* __restrict__ hs, const float4* __restrict__ wqkv,
                   const float4* __restrict__ wz, const float4* __restrict__ wb,
                   const float4* __restrict__ wa,
                   ushort4* __restrict__ hsH4, ushort4* __restrict__ hsL4,
                   ushort4* __restrict__ WH4, ushort4* __restrict__ WL4) {
    int i = blockIdx.x * 256 + threadIdx.x;
    const float4* src; ushort4* dh; ushort4* dl; int j;
    if (i < N4_HS)                          { j = i;                       src = hs;   dh = hsH4; dl = hsL4; }
    else if ((j = i - N4_HS) < N4_QKV)      {                              src = wqkv; dh = WH4;  dl = WL4; }
    else if ((j -= N4_QKV) < N4_Z)          { src = wz; dh = WH4 + N4_QKV;            dl = WL4 + N4_QKV; }
    else if ((j -= N4_Z) < N4_BA)           { src = wb; dh = WH4 + N4_QKV + N4_Z;     dl = WL4 + N4_QKV + N4_Z; }
    else                                    { j -= N4_BA;
                                              src = wa; dh = WH4 + N4_QKV + N4_Z + N4_BA;
                                                        dl = WL4 + N4_QKV + N4_Z + N4_BA; }
    float4 v = src[j];
    ushort4 h, l; cvt4(v, h, l);
    dh[j] = h; dl[j] = l;
}

// ---------------- big GEMM, 256x256 tile, 4-slot ring, counted vmcnt --------
// PROVEN FORM (round 1/7: FETCH ~160MB, conflicts 0). 196 blocks, one full-K
// tile per block, direct stores. Panel-major XCD swizzle keeps the 4 m-tiles
// of each n-panel concurrent on one XCD -> B weights fetched ~once.
// NOTE: no extra work folded into this kernel — the whole WH/WL overlay
// region is live-read here (round-6 aliasing bug).
__global__ __launch_bounds__(512, 2)
void gemm_big256(const ushort* __restrict__ Ah, const ushort* __restrict__ Al,
                 const ushort* __restrict__ Bh, const ushort* __restrict__ Bl,
                 float* __restrict__ xBC, float* __restrict__ zq)
{
    __shared__ ushort lds[4][2][256][32];

    const int tid  = threadIdx.x;
    const int lane = tid & 63, wv = tid >> 6;

    int id = blockIdx.x;
    const int qx = GB_BLOCKS / 8, rx = GB_BLOCKS % 8;       // 24, 4
    int xcd = id & 7, lid = id >> 3;
    int sw  = (xcd < rx) ? (xcd * (qx + 1) + lid)
                         : (rx * (qx + 1) + (xcd - rx) * qx + lid);
    const int m0 = (sw & 3) << 8;
    const int n0 = (sw >> 2) << 8;

    const int rb  = (wv << 4) + (lane >> 2);
    const int csw = (((lane & 3) ^ ((lane >> 3) & 3)) << 3);

    auto stage = [&](int kt, int slot) {
        int third = kt / 80;
        int kk = (kt - third * 80) * BKT;
        const ushort* Ap = (third == 2) ? Al : Ah;   // [Ah, Ah, Al]
        const ushort* Bp = (third == 1) ? Bl : Bh;   // [Bh, Bl, Bh]
        int cs = kk + csw;
        int ar0 = m0 + rb, ar1 = m0 + 128 + rb;
        int br0 = n0 + rb;        if (br0 > NBIG - 1) br0 = NBIG - 1;
        int br1 = n0 + 128 + rb;  if (br1 > NBIG - 1) br1 = NBIG - 1;
        ushort* dA = &lds[slot][0][wv << 4][0];
        ushort* dB = &lds[slot][1][wv << 4][0];
        async16(Ap + (size_t)ar0 * HID + cs, dA);
        async16(Ap + (size_t)ar1 * HID + cs, dA + 128 * 32);
        async16(Bp + (size_t)br0 * HID + cs, dB);
        async16(Bp + (size_t)br1 * HID + cs, dB + 128 * 32);
    };

    const int wm  = (wv >> 2) << 7;
    const int wn  = (wv & 3) << 6;
    const int fr  = lane & 15;
    const int ckr = ((((lane >> 4) ^ ((lane >> 1) & 3))) << 3);

    f32x4 acc[8][4];
    #pragma unroll
    for (int i = 0; i < 8; i++)
        #pragma unroll
        for (int j = 0; j < 4; j++) acc[i][j] = (f32x4){0.f, 0.f, 0.f, 0.f};

    auto compute = [&](int slot) {
        const ushort* sA = &lds[slot][0][0][0];
        const ushort* sB = &lds[slot][1][0][0];
        bf16x8 a[8], b[4];
        #pragma unroll
        for (int mt = 0; mt < 8; mt++)
            a[mt] = *(const bf16x8*)&sA[(wm + mt * 16 + fr) * 32 + ckr];
        #pragma unroll
        for (int nt = 0; nt < 4; nt++)
            b[nt] = *(const bf16x8*)&sB[(wn + nt * 16 + fr) * 32 + ckr];
        __builtin_amdgcn_s_setprio(1);
        #pragma unroll
        for (int mt = 0; mt < 8; mt++)
            #pragma unroll
            for (int nt = 0; nt < 4; nt++)
                acc[mt][nt] = __builtin_amdgcn_mfma_f32_16x16x32_bf16(
                    a[mt], b[nt], acc[mt][nt], 0, 0, 0);
        __builtin_amdgcn_s_setprio(0);
    };

    stage(0, 0); stage(1, 1); stage(2, 2);

    #pragma unroll 4
    for (int kt = 0; kt < NKT - 4; kt++) {
        gate_barrier<8>();
        stage(kt + 3, (kt + 3) & 3);
        compute(kt & 3);
    }
    gate_barrier<8>(); stage(239, 3); compute(0);
    gate_barrier<8>(); compute(1);
    gate_barrier<4>(); compute(2);
    gate_barrier<0>(); compute(3);

    const int rq = (lane >> 4) << 2;
    #pragma unroll
    for (int mt = 0; mt < 8; mt++) {
        int row = m0 + wm + mt * 16 + rq;
        #pragma unroll
        for (int nt = 0; nt < 4; nt++) {
            int col = n0 + wn + nt * 16 + fr;
            if (col < 8192) {
                #pragma unroll
                for (int r = 0; r < 4; r++)
                    xBC[(size_t)(row + r) * 8192 + col] = acc[mt][nt][r];
            } else if (col < NBIG) {
                #pragma unroll
                for (int r = 0; r < 4; r++)
                    zq[(size_t)(row + r) * NZ + (col - 8192)] = acc[mt][nt][r];
            }
        }
    }
}

// ---------------- phase-2 fused: conv+SiLU | W_out cvt | dt_scan ------------
// All three depend only on gemm_big256 outputs and are mutually independent.
// 1024-thread blocks, role-partitioned grid:
//   [0, 2048):        causal conv K=4 + SiLU, float4-vectorized
//   [2048, 4608):     W_out f32 -> (hi,lo) bf16 planes (after gemm_big: WoH/WoL
//                     alias the WL region, which is dead only now)
//   [4608, 4640):     dt softplus + cumsum scan (one block per group)
#define CONV_BLKS 2048
#define WOUT_BLKS 2560
#define DT_BLKS   NG
__global__ __launch_bounds__(1024)
void phase2_fused(const float4* __restrict__ xBC4, const float4* __restrict__ cw4,
                  float4* __restrict__ xconv4,
                  const float4* __restrict__ Wout_src,
                  ushort4* __restrict__ WoH4, ushort4* __restrict__ WoL4,
                  const float* __restrict__ zq,
                  const float* __restrict__ A_log, const float* __restrict__ dt_bias,
                  float* __restrict__ dt_soft, float* __restrict__ Sbuf,
                  float* __restrict__ Ebuf) {
    const int tid = threadIdx.x;
    if (blockIdx.x < CONV_BLKS) {
        // ---- conv: one float4 (4 channels, same t) per thread ----
        int idx4 = blockIdx.x * 1024 + tid;          // < 2,097,152
        int t  = idx4 >> 11;                          // / (D_INNER/4 = 2048)
        int c4 = idx4 & 2047;
        // per-channel taps: conv_w[c][k] contiguous -> one float4 per channel
        float4 w0 = cw4[c4 * 4 + 0], w1 = cw4[c4 * 4 + 1];
        float4 w2 = cw4[c4 * 4 + 2], w3 = cw4[c4 * 4 + 3];
        float4 acc = {0.f, 0.f, 0.f, 0.f};
        #pragma unroll
        for (int k = 0; k < KCONV; k++) {
            int tt = t - (KCONV - 1) + k;
            if (tt >= 0) {
                float4 x = xBC4[(size_t)tt * 2048 + c4];
                float t0 = (k == 0) ? w0.x : (k == 1) ? w0.y : (k == 2) ? w0.z : w0.w;
                float t1 = (k == 0) ? w1.x : (k == 1) ? w1.y : (k == 2) ? w1.z : w1.w;
                float t2 = (k == 0) ? w2.x : (k == 1) ? w2.y : (k == 2) ? w2.z : w2.w;
                float t3 = (k == 0) ? w3.x : (k == 1) ? w3.y : (k == 2) ? w3.z : w3.w;
                acc.x += x.x * t0; acc.y += x.y * t1;
                acc.z += x.z * t2; acc.w += x.w * t3;
            }
        }
        acc.x = siluf(acc.x); acc.y = siluf(acc.y);
        acc.z = siluf(acc.z); acc.w = siluf(acc.w);
        xconv4[idx4] = acc;
    } else if (blockIdx.x < CONV_BLKS + WOUT_BLKS) {
        // ---- W_out split-convert ----
        int i = (blockIdx.x - CONV_BLKS) * 1024 + tid;   // < 2,621,440
        float4 v = Wout_src[i];
        ushort4 h, l; cvt4(v, h, l);
        WoH4[i] = h; WoL4[i] = l;
    } else {
        // ---- dt softplus + cumsum (unchanged proven code) ----
        const int g = blockIdx.x - (CONV_BLKS + WOUT_BLKS);
        const int t = tid;
        __shared__ float buf0[LSEQ], buf1[LSEQ];
        float dtr = zq[(size_t)t * NZ + D_SSM + g] + dt_bias[g];
        float dt = (dtr > 20.f) ? dtr : log1pf(expf(dtr));
        dt_soft[g * LSEQ + t] = dt;
        buf0[t] = dt;
        __syncthreads();
        float* src = buf0; float* dst = buf1;
        for (int off = 1; off < LSEQ; off <<= 1) {
            float v = src[t];
            if (t >= off) v += src[t - off];
            dst[t] = v;
            __syncthreads();
            float* tmp = src; src = dst; dst = tmp;
        }
        float A = -expf(A_log[g]);
        float S = A * src[t];
        Sbuf[g * LSEQ + t] = S;
        if ((t & (LC - 1)) == LC - 1) Ebuf[g * NC + (t >> 6)] = S;
    }
}

// ---------------- out GEMM: 256^2 tiles, split-K x6, 240 blocks -------------
__global__ __launch_bounds__(512, 2)
void gemm_out_sk256(const ushort* __restrict__ Ah, const ushort* __restrict__ Al,
                    const ushort* __restrict__ Bh, const ushort* __restrict__ Bl,
                    float* __restrict__ C)
{
    constexpr int LDA = D_SSM;
    constexpr int KT3 = 128;

    __shared__ ushort lds[4][2][256][32];

    const int tid  = threadIdx.x;
    const int lane = tid & 63, wv = tid >> 6;

    const int bid = blockIdx.x;
    const int wid = (bid & 7) * 30 + (bid >> 3);
    const int m   = wid & 3;
    const int q   = wid >> 2;
    const int n   = q % 10;
    const int kz  = q / 10;
    const int m0  = m << 8, n0 = n << 8;
    const int kt0 = kz * 64;

    const int rb  = (wv << 4) + (lane >> 2);
    const int csw = (((lane & 3) ^ ((lane >> 3) & 3)) << 3);
    const int wm  = (wv >> 2) << 7;
    const int wn  = (wv & 3) << 6;
    const int fr  = lane & 15;
    const int ckr = (((lane >> 4) ^ ((lane >> 1) & 3)) << 3);
    const int rq  = (lane >> 4) << 2;

    auto stage = [&](int kt, int slot) {
        int third = kt / KT3;
        int kk = (kt - third * KT3) * BKT;
        const ushort* Ap = (third == 2) ? Al : Ah;
        const ushort* Bp = (third == 1) ? Bl : Bh;
        int cs = kk + csw;
        ushort* dA = &lds[slot][0][wv << 4][0];
        ushort* dB = &lds[slot][1][wv << 4][0];
        async16(Ap + (size_t)(m0 + rb) * LDA + cs, dA);
        async16(Ap + (size_t)(m0 + 128 + rb) * LDA + cs, dA + 128 * 32);
        async16(Bp + (size_t)(n0 + rb) * LDA + cs, dB);
        async16(Bp + (size_t)(n0 + 128 + rb) * LDA + cs, dB + 128 * 32);
    };

    f32x4 acc[8][4];
    #pragma unroll
    for (int i = 0; i < 8; i++)
        #pragma unroll
        for (int j = 0; j < 4; j++) acc[i][j] = (f32x4){0.f, 0.f, 0.f, 0.f};

    auto compute = [&](int slot) {
        const ushort* sA = &lds[slot][0][0][0];
        const ushort* sB = &lds[slot][1][0][0];
        bf16x8 a[8], b[4];
        #pragma unroll
        for (int mt = 0; mt < 8; mt++)
            a[mt] = *(const bf16x8*)&sA[(wm + mt * 16 + fr) * 32 + ckr];
        #pragma unroll
        for (int nt = 0; nt < 4; nt++)
            b[nt] = *(const bf16x8*)&sB[(wn + nt * 16 + fr) * 32 + ckr];
        __builtin_amdgcn_s_setprio(1);
        #pragma unroll
        for (int mt = 0; mt < 8; mt++)
            #pragma unroll
            for (int nt = 0; nt < 4; nt++)
                acc[mt][nt] = __builtin_amdgcn_mfma_f32_16x16x32_bf16(
                    a[mt], b[nt], acc[mt][nt], 0, 0, 0);
        __builtin_amdgcn_s_setprio(0);
    };

    stage(kt0 + 0, 0); stage(kt0 + 1, 1); stage(kt0 + 2, 2);
    #pragma unroll 4
    for (int i = 0; i < 60; i++) {
        gate_barrier<8>();
        stage(kt0 + i + 3, (i + 3) & 3);
        compute(i & 3);
    }
    gate_barrier<8>(); stage(kt0 + 63, 63 & 3); compute(60 & 3);
    gate_barrier<8>(); compute(61 & 3);
    gate_barrier<4>(); compute(62 & 3);
    gate_barrier<0>(); compute(63 & 3);

    #pragma unroll
    for (int mt = 0; mt < 8; mt++) {
        int row = m0 + wm + mt * 16 + rq;
        #pragma unroll
        for (int nt = 0; nt < 4; nt++) {
            int col = n0 + wn + nt * 16 + fr;
            #pragma unroll
            for (int r = 0; r < 4; r++)
                atomicAdd(&C[(size_t)(row + r) * HID + col], acc[mt][nt][r]);
        }
    }
}

// ---------------- S2: chunk states ----------------
__global__ __launch_bounds__(256)
void chunk_state(const float* __restrict__ xc, const float* __restrict__ dt_soft,
                 const float* __restrict__ Sbuf, const float* __restrict__ Ebuf,
                 float* __restrict__ Sc) {
    const int g = blockIdx.x, c = blockIdx.y;
    const int tid = threadIdx.x;
    const int t0 = c * LC;
    __shared__ __align__(16) float wB[LC][DS];
    __shared__ float Xs[LC][HD];
    __shared__ float sw[LC];

    if (tid < LC) {
        float Ec = Ebuf[g * NC + c];
        sw[tid] = expf(Ec - Sbuf[g * LSEQ + t0 + tid]) * dt_soft[g * LSEQ + t0 + tid];
    }
    __syncthreads();
    for (int i = tid; i < LC * DS; i += 256) {
        int r = i >> 6, s = i & 63;
        wB[r][s] = sw[r] * xc[(size_t)(t0 + r) * D_INNER + D_SSM + g * DS + s];
    }
    for (int i = tid; i < LC * HD; i += 256) {
        int r = i >> 7, h = i & 127;
        Xs[r][h] = xc[(size_t)(t0 + r) * D_INNER + g * HD + h];
    }
    __syncthreads();

    const int h = tid & 127, sh = (tid >> 7) * 32;
    float acc[32];
    #pragma unroll
    for (int j = 0; j < 32; j++) acc[j] = 0.f;
    for (int r = 0; r < LC; r++) {
        float xv = Xs[r][h];
        const float4* wrow = (const float4*)&wB[r][sh];
        #pragma unroll
        for (int q = 0; q < 8; q++) {
            float4 w4 = wrow[q];
            acc[4*q+0] += w4.x * xv;
            acc[4*q+1] += w4.y * xv;
            acc[4*q+2] += w4.z * xv;
            acc[4*q+3] += w4.w * xv;
        }
    }
    float* out = Sc + (size_t)(g * NC + c) * DS * HD;
    #pragma unroll
    for (int j = 0; j < 32; j++) out[(size_t)(sh + j) * HD + h] = acc[j];
}

// ---------------- S3: prefix over chunks ----------------
__global__ __launch_bounds__(256)
void chunk_prefix(const float* __restrict__ Sc, const float* __restrict__ Ebuf,
                  float* __restrict__ Hbuf) {
    const int g = blockIdx.y;
    const int e = blockIdx.x * 256 + threadIdx.x;
    float H = 0.f, Eprev = 0.f;
    for (int c = 0; c < NC; c++) {
        size_t base = (size_t)(g * NC + c) * DS * HD;
        Hbuf[base + e] = H;
        float Ec = Ebuf[g * NC + c];
        H = expf(Ec - Eprev) * H + Sc[base + e];
        Eprev = Ec;
    }
}

// ---------------- S4: per-chunk output + RMSNorm + SiLU(z), emits yg hi/lo ----
__global__ __launch_bounds__(256)
void chunk_output(const float* __restrict__ xc, const float* __restrict__ dt_soft,
                  const float* __restrict__ Sbuf, const float* __restrict__ Ebuf,
                  const float* __restrict__ Hbuf,
                  const float* __restrict__ zq, const float* __restrict__ norm_w,
                  ushort* __restrict__ ygH, ushort* __restrict__ ygL) {
    const int g = blockIdx.x, c = blockIdx.y;
    const int tid = threadIdx.x;
    const int t0 = c * LC;

    __shared__ __align__(16) float smem[4096 + 4096 + 8192];
    float* CT = smem;
    float* BW = smem + 4096;
    float* Xs = smem + 8192;
    float* red = smem;
    float* sscale = smem + 256;

    for (int i = tid; i < LC * DS; i += 256) {
        int t = i >> 6, s = i & 63;
        CT[s * LC + t] = xc[(size_t)(t0 + t) * D_INNER + D_SSM + NG * DS + g * DS + s];
        BW[t * DS + s] = xc[(size_t)(t0 + t) * D_INNER + D_SSM + g * DS + s];
    }
    for (int i = tid; i < LC * HD; i += 256) {
        int t = i >> 7, h = i & 127;
        Xs[t * HD + h] = xc[(size_t)(t0 + t) * D_INNER + g * HD + h];
    }
    __syncthreads();

    {
        const int t = tid & 63, tau0 = tid >> 6;
        float Greg[16];
        #pragma unroll
        for (int k = 0; k < 16; k++) Greg[k] = 0.f;
        for (int s = 0; s < DS; s++) {
            float cv = CT[s * LC + t];
            #pragma unroll
            for (int k = 0; k < 16; k++) Greg[k] += cv * BW[(tau0 + 4 * k) * DS + s];
        }
        __syncthreads();
        float St = Sbuf[g * LSEQ + t0 + t];
        #pragma unroll
        for (int k = 0; k < 16; k++) {
            int tau = tau0 + 4 * k;
            float w = 0.f;
            if (tau <= t)
                w = expf(St - Sbuf[g * LSEQ + t0 + tau]) *
                    dt_soft[g * LSEQ + t0 + tau] * Greg[k];
            BW[tau * LC + t] = w;
        }
    }
    __syncthreads();

    const int h = tid & 127, tb = (tid >> 7) * 32;
    float y[32], T[32];
    #pragma unroll
    for (int j = 0; j < 32; j++) { y[j] = 0.f; T[j] = 0.f; }

    for (int tau = 0; tau < LC; tau++) {
        float xv = Xs[tau * HD + h];
        const float4* wrow = (const float4*)&BW[tau * LC + tb];
        #pragma unroll
        for (int q = 0; q < 8; q++) {
            float4 w4 = wrow[q];
            y[4*q+0] += w4.x * xv;
            y[4*q+1] += w4.y * xv;
            y[4*q+2] += w4.z * xv;
            y[4*q+3] += w4.w * xv;
        }
    }
    {
        const float* Hg = Hbuf + (size_t)(g * NC + c) * DS * HD;
        for (int s = 0; s < DS; s++) {
            float Hv = Hg[(size_t)s * HD + h];
            const float* crow = &CT[s * LC + tb];
            #pragma unroll
            for (int j = 0; j < 32; j++) T[j] += crow[j] * Hv;
        }
    }
    float Eprev = (c > 0) ? Ebuf[g * NC + c - 1] : 0.f;
    #pragma unroll
    for (int j = 0; j < 32; j++) {
        int t = tb + j;
        float St = Sbuf[g * LSEQ + t0 + t];
        float Dv = zq[(size_t)(t0 + t) * NZ + D_SSM + NG + g];
        y[j] += expf(St - Eprev) * T[j] + Dv * Xs[t * HD + h];
    }
    __syncthreads();
    #pragma unroll
    for (int j = 0; j < 32; j++) Xs[(tb + j) * HD + h] = y[j];
    __syncthreads();

    {
        int t = tid >> 2, q = tid & 3;
        float p = 0.f;
        for (int i = 0; i < 32; i++) {
            float v = Xs[t * HD + q * 32 + i];
            p += v * v;
        }
        red[t * 4 + q] = p;
    }
    __syncthreads();
    if (tid < LC) {
        float s2 = red[tid*4] + red[tid*4+1] + red[tid*4+2] + red[tid*4+3];
        sscale[tid] = rsqrtf(s2 * (1.f / HD) + EPS_RMS);
    }
    __syncthreads();

    float nw = norm_w[h];
    #pragma unroll
    for (int j = 0; j < 32; j++) {
        int t = tb + j;
        float zv = zq[(size_t)(t0 + t) * NZ + g * HD + h];
        size_t idx = (size_t)(t0 + t) * D_SSM + g * HD + h;
        float val = y[j] * sscale[t] * nw * siluf(zv);
        unsigned short hb = f2bf(val);
        ygH[idx] = hb;
        ygL[idx] = f2bf(val - bf2f(hb));
    }
}

extern "C" void kernel_launch(void* const* d_in, const int* in_sizes, int n_in,
                              void* d_out, int out_size, void* d_ws, size_t ws_size,
                              hipStream_t stream) {
    const float* hs      = (const float*)d_in[0];
    const float* W_qkv   = (const float*)d_in[1];
    const float* W_z     = (const float*)d_in[2];
    const float* W_a     = (const float*)d_in[3];
    const float* W_b     = (const float*)d_in[4];
    const float* conv_w  = (const float*)d_in[5];
    const float* W_out   = (const float*)d_in[6];
    const float* norm_w  = (const float*)d_in[7];
    const float* A_log   = (const float*)d_in[8];
    const float* dt_bias = (const float*)d_in[9];
    float* out = (float*)d_out;

    float* ws      = (float*)d_ws;
    float* xBC     = ws;                                   // 8,388,608 f
    float* zq      = xBC + (size_t)LSEQ * D_INNER;         // 4,325,376 f
    float* dt_soft = zq + (size_t)LSEQ * NZ;               // 32768 f
    float* Sbuf    = dt_soft + (size_t)NG * LSEQ;          // 32768 f
    float* Ebuf    = Sbuf + (size_t)NG * LSEQ;             // 512 f
    ushort* hsH    = (ushort*)(Ebuf + 512);                // 2,621,440 us
    ushort* hsL    = hsH + (size_t)LSEQ * HID;
    ushort* WH     = hsL + (size_t)LSEQ * HID;             // NBIG*HID = 31,784,960 us
    ushort* WL     = WH + (size_t)NBIG * HID;
    // phase-2 overlay on WH/WL region (dead after gemm_big256):
    float* xconv   = (float*)WH;                           // 8,388,608 f
    float* Sc      = xconv + (size_t)LSEQ * D_INNER;       // 4,194,304 f
    float* Hbuf    = Sc + (size_t)NG * NC * DS * HD;       // 4,194,304 f
    ushort* ygH    = (ushort*)(Hbuf + (size_t)NG * NC * DS * HD);  // 4,194,304 us
    ushort* ygL    = ygH + (size_t)LSEQ * D_SSM;
    ushort* WoH    = ygL + (size_t)LSEQ * D_SSM;           // 10,485,760 us
    ushort* WoL    = WoH + (size_t)HID * D_SSM;

    // 1) all input planes in one kernel (was 5 launches)
    split_cvt_all<<<dim3(33440), dim3(256), 0, stream>>>(
        (const float4*)hs, (const float4*)W_qkv, (const float4*)W_z,
        (const float4*)W_b, (const float4*)W_a,
        (ushort4*)hsH, (ushort4*)hsL, (ushort4*)WH, (ushort4*)WL);

    // 2) merged projection GEMM: 196 blocks, proven form
    gemm_big256<<<dim3(GB_BLOCKS), dim3(512), 0, stream>>>(
        hsH, hsL, WH, WL, xBC, zq);

    // 3) conv+SiLU | W_out planes | dt-scan in one kernel (was 3 launches)
    phase2_fused<<<dim3(CONV_BLKS + WOUT_BLKS + DT_BLKS), dim3(1024), 0, stream>>>(
        (const float4*)xBC, (const float4*)conv_w, (float4*)xconv,
        (const float4*)W_out, (ushort4*)WoH, (ushort4*)WoL,
        zq, A_log, dt_bias, dt_soft, Sbuf, Ebuf);

    dim3 blk(256);
    chunk_state<<<dim3(NG, NC), blk, 0, stream>>>(xconv, dt_soft, Sbuf, Ebuf, Sc);
    chunk_prefix<<<dim3(DS * HD / 256, NG), blk, 0, stream>>>(Sc, Ebuf, Hbuf);
    chunk_output<<<dim3(NG, NC), blk, 0, stream>>>(xconv, dt_soft, Sbuf, Ebuf,
                                                   Hbuf, zq, norm_w, ygH, ygL);

    // out = yg @ W_out^T: 240-block 256^2 split-K x6, atomic accumulate
    hipMemsetAsync(out, 0, (size_t)LSEQ * HID * sizeof(float), stream);
    gemm_out_sk256<<<dim3(240), dim3(512), 0, stream>>>(
        ygH, ygL, WoH, WoL, out);
}

// Round 9
// 580.656 us; speedup vs baseline: 1.2360x; 1.0543x over previous
//
#include <hip/hip_runtime.h>
#include <hip/hip_bf16.h>
#include <math.h>

#define HID     2560
#define D_INNER 8192
#define NG      32
#define D_SSM   4096
#define KCONV   4
#define HD      128
#define DS      64
#define LSEQ    1024
#define LC      64
#define NC      (LSEQ / LC)
#define NZ      4224          // z(4096) + dt(32) + D(32) + pad(64)
#define NBIG    12416         // qkv(8192) + NZ
#define EPS_RMS 1e-6f

// ---- gemm_big256 deep-pipeline params ----
#define BKT       32          // K per tile (one 16x16x32 MFMA k-depth)
#define NKT       240         // K' = 3*2560 -> 240 tiles of 32
#define GB_BLOCKS 196         // 49 n-tiles * 4 m-tiles

typedef short bf16x8 __attribute__((ext_vector_type(8)));
typedef float f32x4 __attribute__((ext_vector_type(4)));

__device__ __forceinline__ float siluf(float x) { return x / (1.f + expf(-x)); }

__device__ __forceinline__ unsigned short f2bf(float x) {
    __hip_bfloat16 b = __float2bfloat16(x);
    return *reinterpret_cast<unsigned short*>(&b);
}
__device__ __forceinline__ float bf2f(unsigned short u) {
    union { unsigned int i; float f; } v;
    v.i = ((unsigned int)u) << 16;
    return v.f;
}

__device__ __forceinline__ void async16(const ushort* g, ushort* l) {
    __builtin_amdgcn_global_load_lds(
        (const __attribute__((address_space(1))) unsigned int*)g,
        (__attribute__((address_space(3))) unsigned int*)l, 16, 0, 0);
}

// counted-vmcnt gate: drain own ds_reads (lgkmcnt 0), leave VM staging loads
// in flight across the raw barrier (T4). Compile-time VM only.
template<int VM>
__device__ __forceinline__ void gate_barrier() {
    asm volatile("s_waitcnt vmcnt(%0) lgkmcnt(0)" :: "n"(VM) : "memory");
    __builtin_amdgcn_s_barrier();
    asm volatile("" ::: "memory");
}

__device__ __forceinline__ void cvt4(const float4& v, ushort4& h, ushort4& l) {
    h.x = f2bf(v.x); l.x = f2bf(v.x - bf2f(h.x));
    h.y = f2bf(v.y); l.y = f2bf(v.y - bf2f(h.y));
    h.z = f2bf(v.z); l.z = f2bf(v.z - bf2f(h.z));
    h.w = f2bf(v.w); l.w = f2bf(v.w - bf2f(h.w));
}

// ---------------- fused input-plane conversion (5 launches -> 1) -----------
#define N4_HS   (LSEQ * HID / 4)
#define N4_QKV  (D_INNER * HID / 4)
#define N4_Z    (D_SSM * HID / 4)
#define N4_BA   (NG * HID / 4)
__global__ __launch_bounds__(256)
void split_cvt_all(const float4* __restrict__ hs, const float4* __restrict__ wqkv,
                   const float4* __restrict__ wz, const float4* __restrict__ wb,
                   const float4* __restrict__ wa,
                   ushort4* __restrict__ hsH4, ushort4* __restrict__ hsL4,
                   ushort4* __restrict__ WH4, ushort4* __restrict__ WL4) {
    int i = blockIdx.x * 256 + threadIdx.x;
    const float4* src; ushort4* dh; ushort4* dl; int j;
    if (i < N4_HS)                          { j = i;                       src = hs;   dh = hsH4; dl = hsL4; }
    else if ((j = i - N4_HS) < N4_QKV)      {                              src = wqkv; dh = WH4;  dl = WL4; }
    else if ((j -= N4_QKV) < N4_Z)          { src = wz; dh = WH4 + N4_QKV;            dl = WL4 + N4_QKV; }
    else if ((j -= N4_Z) < N4_BA)           { src = wb; dh = WH4 + N4_QKV + N4_Z;     dl = WL4 + N4_QKV + N4_Z; }
    else                                    { j -= N4_BA;
                                              src = wa; dh = WH4 + N4_QKV + N4_Z + N4_BA;
                                                        dl = WL4 + N4_QKV + N4_Z + N4_BA; }
    float4 v = src[j];
    ushort4 h, l; cvt4(v, h, l);
    dh[j] = h; dl[j] = l;
}

// ---------------- big GEMM, 256x256 tile, 4-slot ring, counted vmcnt --------
// PROVEN FORM (rounds 1/7/8: FETCH ~160MB, conflicts 0). 196 blocks, one
// full-K tile per block, direct stores. Panel-major XCD swizzle keeps the 4
// m-tiles of each n-panel concurrent on one XCD -> B weights fetched ~once.
__global__ __launch_bounds__(512, 2)
void gemm_big256(const ushort* __restrict__ Ah, const ushort* __restrict__ Al,
                 const ushort* __restrict__ Bh, const ushort* __restrict__ Bl,
                 float* __restrict__ xBC, float* __restrict__ zq)
{
    __shared__ ushort lds[4][2][256][32];

    const int tid  = threadIdx.x;
    const int lane = tid & 63, wv = tid >> 6;

    int id = blockIdx.x;
    const int qx = GB_BLOCKS / 8, rx = GB_BLOCKS % 8;       // 24, 4
    int xcd = id & 7, lid = id >> 3;
    int sw  = (xcd < rx) ? (xcd * (qx + 1) + lid)
                         : (rx * (qx + 1) + (xcd - rx) * qx + lid);
    const int m0 = (sw & 3) << 8;
    const int n0 = (sw >> 2) << 8;

    const int rb  = (wv << 4) + (lane >> 2);
    const int csw = (((lane & 3) ^ ((lane >> 3) & 3)) << 3);

    auto stage = [&](int kt, int slot) {
        int third = kt / 80;
        int kk = (kt - third * 80) * BKT;
        const ushort* Ap = (third == 2) ? Al : Ah;   // [Ah, Ah, Al]
        const ushort* Bp = (third == 1) ? Bl : Bh;   // [Bh, Bl, Bh]
        int cs = kk + csw;
        int ar0 = m0 + rb, ar1 = m0 + 128 + rb;
        int br0 = n0 + rb;        if (br0 > NBIG - 1) br0 = NBIG - 1;
        int br1 = n0 + 128 + rb;  if (br1 > NBIG - 1) br1 = NBIG - 1;
        ushort* dA = &lds[slot][0][wv << 4][0];
        ushort* dB = &lds[slot][1][wv << 4][0];
        async16(Ap + (size_t)ar0 * HID + cs, dA);
        async16(Ap + (size_t)ar1 * HID + cs, dA + 128 * 32);
        async16(Bp + (size_t)br0 * HID + cs, dB);
        async16(Bp + (size_t)br1 * HID + cs, dB + 128 * 32);
    };

    const int wm  = (wv >> 2) << 7;
    const int wn  = (wv & 3) << 6;
    const int fr  = lane & 15;
    const int ckr = ((((lane >> 4) ^ ((lane >> 1) & 3))) << 3);

    f32x4 acc[8][4];
    #pragma unroll
    for (int i = 0; i < 8; i++)
        #pragma unroll
        for (int j = 0; j < 4; j++) acc[i][j] = (f32x4){0.f, 0.f, 0.f, 0.f};

    auto compute = [&](int slot) {
        const ushort* sA = &lds[slot][0][0][0];
        const ushort* sB = &lds[slot][1][0][0];
        bf16x8 a[8], b[4];
        #pragma unroll
        for (int mt = 0; mt < 8; mt++)
            a[mt] = *(const bf16x8*)&sA[(wm + mt * 16 + fr) * 32 + ckr];
        #pragma unroll
        for (int nt = 0; nt < 4; nt++)
            b[nt] = *(const bf16x8*)&sB[(wn + nt * 16 + fr) * 32 + ckr];
        __builtin_amdgcn_s_setprio(1);
        #pragma unroll
        for (int mt = 0; mt < 8; mt++)
            #pragma unroll
            for (int nt = 0; nt < 4; nt++)
                acc[mt][nt] = __builtin_amdgcn_mfma_f32_16x16x32_bf16(
                    a[mt], b[nt], acc[mt][nt], 0, 0, 0);
        __builtin_amdgcn_s_setprio(0);
    };

    stage(0, 0); stage(1, 1); stage(2, 2);

    #pragma unroll 4
    for (int kt = 0; kt < NKT - 4; kt++) {
        gate_barrier<8>();
        stage(kt + 3, (kt + 3) & 3);
        compute(kt & 3);
    }
    gate_barrier<8>(); stage(239, 3); compute(0);
    gate_barrier<8>(); compute(1);
    gate_barrier<4>(); compute(2);
    gate_barrier<0>(); compute(3);

    const int rq = (lane >> 4) << 2;
    #pragma unroll
    for (int mt = 0; mt < 8; mt++) {
        int row = m0 + wm + mt * 16 + rq;
        #pragma unroll
        for (int nt = 0; nt < 4; nt++) {
            int col = n0 + wn + nt * 16 + fr;
            if (col < 8192) {
                #pragma unroll
                for (int r = 0; r < 4; r++)
                    xBC[(size_t)(row + r) * 8192 + col] = acc[mt][nt][r];
            } else if (col < NBIG) {
                #pragma unroll
                for (int r = 0; r < 4; r++)
                    zq[(size_t)(row + r) * NZ + (col - 8192)] = acc[mt][nt][r];
            }
        }
    }
}

// ---------------- phase-2 fused: conv+SiLU | W_out cvt | dt_scan ------------
#define CONV_BLKS 2048
#define WOUT_BLKS 2560
#define DT_BLKS   NG
__global__ __launch_bounds__(1024)
void phase2_fused(const float4* __restrict__ xBC4, const float4* __restrict__ cw4,
                  float4* __restrict__ xconv4,
                  const float4* __restrict__ Wout_src,
                  ushort4* __restrict__ WoH4, ushort4* __restrict__ WoL4,
                  const float* __restrict__ zq,
                  const float* __restrict__ A_log, const float* __restrict__ dt_bias,
                  float* __restrict__ dt_soft, float* __restrict__ Sbuf,
                  float* __restrict__ Ebuf) {
    const int tid = threadIdx.x;
    if (blockIdx.x < CONV_BLKS) {
        int idx4 = blockIdx.x * 1024 + tid;
        int t  = idx4 >> 11;
        int c4 = idx4 & 2047;
        float4 w0 = cw4[c4 * 4 + 0], w1 = cw4[c4 * 4 + 1];
        float4 w2 = cw4[c4 * 4 + 2], w3 = cw4[c4 * 4 + 3];
        float4 acc = {0.f, 0.f, 0.f, 0.f};
        #pragma unroll
        for (int k = 0; k < KCONV; k++) {
            int tt = t - (KCONV - 1) + k;
            if (tt >= 0) {
                float4 x = xBC4[(size_t)tt * 2048 + c4];
                float t0 = (k == 0) ? w0.x : (k == 1) ? w0.y : (k == 2) ? w0.z : w0.w;
                float t1 = (k == 0) ? w1.x : (k == 1) ? w1.y : (k == 2) ? w1.z : w1.w;
                float t2 = (k == 0) ? w2.x : (k == 1) ? w2.y : (k == 2) ? w2.z : w2.w;
                float t3 = (k == 0) ? w3.x : (k == 1) ? w3.y : (k == 2) ? w3.z : w3.w;
                acc.x += x.x * t0; acc.y += x.y * t1;
                acc.z += x.z * t2; acc.w += x.w * t3;
            }
        }
        acc.x = siluf(acc.x); acc.y = siluf(acc.y);
        acc.z = siluf(acc.z); acc.w = siluf(acc.w);
        xconv4[idx4] = acc;
    } else if (blockIdx.x < CONV_BLKS + WOUT_BLKS) {
        int i = (blockIdx.x - CONV_BLKS) * 1024 + tid;
        float4 v = Wout_src[i];
        ushort4 h, l; cvt4(v, h, l);
        WoH4[i] = h; WoL4[i] = l;
    } else {
        const int g = blockIdx.x - (CONV_BLKS + WOUT_BLKS);
        const int t = tid;
        __shared__ float buf0[LSEQ], buf1[LSEQ];
        float dtr = zq[(size_t)t * NZ + D_SSM + g] + dt_bias[g];
        float dt = (dtr > 20.f) ? dtr : log1pf(expf(dtr));
        dt_soft[g * LSEQ + t] = dt;
        buf0[t] = dt;
        __syncthreads();
        float* src = buf0; float* dst = buf1;
        for (int off = 1; off < LSEQ; off <<= 1) {
            float v = src[t];
            if (t >= off) v += src[t - off];
            dst[t] = v;
            __syncthreads();
            float* tmp = src; src = dst; dst = tmp;
        }
        float A = -expf(A_log[g]);
        float S = A * src[t];
        Sbuf[g * LSEQ + t] = S;
        if ((t & (LC - 1)) == LC - 1) Ebuf[g * NC + (t >> 6)] = S;
    }
}

// ---------------- out GEMM: 256^2 tiles, split-K x6, DIRECT partial stores --
// out[1024,2560] = yg @ W_out^T. 240 blocks = 4m x 10n x 6kz (64 kt each).
// Each block stores its partial tile directly (coalesced, non-atomic) into
// P[kz][1024][2560]; reduce6 sums the 6 slabs. Replaces 15.7M fp32 atomicAdds
// whose 96 RMW/cache-line serialization was the suspected ~100us overhead.
__global__ __launch_bounds__(512, 2)
void gemm_out_sk256(const ushort* __restrict__ Ah, const ushort* __restrict__ Al,
                    const ushort* __restrict__ Bh, const ushort* __restrict__ Bl,
                    float* __restrict__ P)
{
    constexpr int LDA = D_SSM;
    constexpr int KT3 = 128;

    __shared__ ushort lds[4][2][256][32];

    const int tid  = threadIdx.x;
    const int lane = tid & 63, wv = tid >> 6;

    const int bid = blockIdx.x;
    const int wid = (bid & 7) * 30 + (bid >> 3);
    const int m   = wid & 3;
    const int q   = wid >> 2;
    const int n   = q % 10;
    const int kz  = q / 10;
    const int m0  = m << 8, n0 = n << 8;
    const int kt0 = kz * 64;

    const int rb  = (wv << 4) + (lane >> 2);
    const int csw = (((lane & 3) ^ ((lane >> 3) & 3)) << 3);
    const int wm  = (wv >> 2) << 7;
    const int wn  = (wv & 3) << 6;
    const int fr  = lane & 15;
    const int ckr = (((lane >> 4) ^ ((lane >> 1) & 3)) << 3);
    const int rq  = (lane >> 4) << 2;

    auto stage = [&](int kt, int slot) {
        int third = kt / KT3;
        int kk = (kt - third * KT3) * BKT;
        const ushort* Ap = (third == 2) ? Al : Ah;
        const ushort* Bp = (third == 1) ? Bl : Bh;
        int cs = kk + csw;
        ushort* dA = &lds[slot][0][wv << 4][0];
        ushort* dB = &lds[slot][1][wv << 4][0];
        async16(Ap + (size_t)(m0 + rb) * LDA + cs, dA);
        async16(Ap + (size_t)(m0 + 128 + rb) * LDA + cs, dA + 128 * 32);
        async16(Bp + (size_t)(n0 + rb) * LDA + cs, dB);
        async16(Bp + (size_t)(n0 + 128 + rb) * LDA + cs, dB + 128 * 32);
    };

    f32x4 acc[8][4];
    #pragma unroll
    for (int i = 0; i < 8; i++)
        #pragma unroll
        for (int j = 0; j < 4; j++) acc[i][j] = (f32x4){0.f, 0.f, 0.f, 0.f};

    auto compute = [&](int slot) {
        const ushort* sA = &lds[slot][0][0][0];
        const ushort* sB = &lds[slot][1][0][0];
        bf16x8 a[8], b[4];
        #pragma unroll
        for (int mt = 0; mt < 8; mt++)
            a[mt] = *(const bf16x8*)&sA[(wm + mt * 16 + fr) * 32 + ckr];
        #pragma unroll
        for (int nt = 0; nt < 4; nt++)
            b[nt] = *(const bf16x8*)&sB[(wn + nt * 16 + fr) * 32 + ckr];
        __builtin_amdgcn_s_setprio(1);
        #pragma unroll
        for (int mt = 0; mt < 8; mt++)
            #pragma unroll
            for (int nt = 0; nt < 4; nt++)
                acc[mt][nt] = __builtin_amdgcn_mfma_f32_16x16x32_bf16(
                    a[mt], b[nt], acc[mt][nt], 0, 0, 0);
        __builtin_amdgcn_s_setprio(0);
    };

    stage(kt0 + 0, 0); stage(kt0 + 1, 1); stage(kt0 + 2, 2);
    #pragma unroll 4
    for (int i = 0; i < 60; i++) {
        gate_barrier<8>();
        stage(kt0 + i + 3, (i + 3) & 3);
        compute(i & 3);
    }
    gate_barrier<8>(); stage(kt0 + 63, 63 & 3); compute(60 & 3);
    gate_barrier<8>(); compute(61 & 3);
    gate_barrier<4>(); compute(62 & 3);
    gate_barrier<0>(); compute(63 & 3);

    // direct (non-atomic) stores into this kz's partial slab
    float* dst = P + (size_t)kz * LSEQ * HID;
    #pragma unroll
    for (int mt = 0; mt < 8; mt++) {
        int row = m0 + wm + mt * 16 + rq;
        #pragma unroll
        for (int nt = 0; nt < 4; nt++) {
            int col = n0 + wn + nt * 16 + fr;
            #pragma unroll
            for (int r = 0; r < 4; r++)
                dst[(size_t)(row + r) * HID + col] = acc[mt][nt][r];
        }
    }
}

// ---------------- reduce the 6 split-K partials into out ----------------
__global__ __launch_bounds__(256)
void reduce6(const float4* __restrict__ P4, float4* __restrict__ out4) {
    const int N4 = LSEQ * HID / 4;       // 655,360
    int i = blockIdx.x * 256 + threadIdx.x;
    float4 s = P4[i];
    #pragma unroll
    for (int kz = 1; kz < 6; kz++) {
        float4 p = P4[(size_t)kz * N4 + i];
        s.x += p.x; s.y += p.y; s.z += p.z; s.w += p.w;
    }
    out4[i] = s;
}

// ---------------- S2: chunk states ----------------
__global__ __launch_bounds__(256)
void chunk_state(const float* __restrict__ xc, const float* __restrict__ dt_soft,
                 const float* __restrict__ Sbuf, const float* __restrict__ Ebuf,
                 float* __restrict__ Sc) {
    const int g = blockIdx.x, c = blockIdx.y;
    const int tid = threadIdx.x;
    const int t0 = c * LC;
    __shared__ __align__(16) float wB[LC][DS];
    __shared__ float Xs[LC][HD];
    __shared__ float sw[LC];

    if (tid < LC) {
        float Ec = Ebuf[g * NC + c];
        sw[tid] = expf(Ec - Sbuf[g * LSEQ + t0 + tid]) * dt_soft[g * LSEQ + t0 + tid];
    }
    __syncthreads();
    for (int i = tid; i < LC * DS; i += 256) {
        int r = i >> 6, s = i & 63;
        wB[r][s] = sw[r] * xc[(size_t)(t0 + r) * D_INNER + D_SSM + g * DS + s];
    }
    for (int i = tid; i < LC * HD; i += 256) {
        int r = i >> 7, h = i & 127;
        Xs[r][h] = xc[(size_t)(t0 + r) * D_INNER + g * HD + h];
    }
    __syncthreads();

    const int h = tid & 127, sh = (tid >> 7) * 32;
    float acc[32];
    #pragma unroll
    for (int j = 0; j < 32; j++) acc[j] = 0.f;
    for (int r = 0; r < LC; r++) {
        float xv = Xs[r][h];
        const float4* wrow = (const float4*)&wB[r][sh];
        #pragma unroll
        for (int q = 0; q < 8; q++) {
            float4 w4 = wrow[q];
            acc[4*q+0] += w4.x * xv;
            acc[4*q+1] += w4.y * xv;
            acc[4*q+2] += w4.z * xv;
            acc[4*q+3] += w4.w * xv;
        }
    }
    float* out = Sc + (size_t)(g * NC + c) * DS * HD;
    #pragma unroll
    for (int j = 0; j < 32; j++) out[(size_t)(sh + j) * HD + h] = acc[j];
}

// ---------------- S3: prefix over chunks ----------------
__global__ __launch_bounds__(256)
void chunk_prefix(const float* __restrict__ Sc, const float* __restrict__ Ebuf,
                  float* __restrict__ Hbuf) {
    const int g = blockIdx.y;
    const int e = blockIdx.x * 256 + threadIdx.x;
    float H = 0.f, Eprev = 0.f;
    for (int c = 0; c < NC; c++) {
        size_t base = (size_t)(g * NC + c) * DS * HD;
        Hbuf[base + e] = H;
        float Ec = Ebuf[g * NC + c];
        H = expf(Ec - Eprev) * H + Sc[base + e];
        Eprev = Ec;
    }
}

// ---------------- S4: per-chunk output + RMSNorm + SiLU(z), emits yg hi/lo ----
__global__ __launch_bounds__(256)
void chunk_output(const float* __restrict__ xc, const float* __restrict__ dt_soft,
                  const float* __restrict__ Sbuf, const float* __restrict__ Ebuf,
                  const float* __restrict__ Hbuf,
                  const float* __restrict__ zq, const float* __restrict__ norm_w,
                  ushort* __restrict__ ygH, ushort* __restrict__ ygL) {
    const int g = blockIdx.x, c = blockIdx.y;
    const int tid = threadIdx.x;
    const int t0 = c * LC;

    __shared__ __align__(16) float smem[4096 + 4096 + 8192];
    float* CT = smem;
    float* BW = smem + 4096;
    float* Xs = smem + 8192;
    float* red = smem;
    float* sscale = smem + 256;

    for (int i = tid; i < LC * DS; i += 256) {
        int t = i >> 6, s = i & 63;
        CT[s * LC + t] = xc[(size_t)(t0 + t) * D_INNER + D_SSM + NG * DS + g * DS + s];
        BW[t * DS + s] = xc[(size_t)(t0 + t) * D_INNER + D_SSM + g * DS + s];
    }
    for (int i = tid; i < LC * HD; i += 256) {
        int t = i >> 7, h = i & 127;
        Xs[t * HD + h] = xc[(size_t)(t0 + t) * D_INNER + g * HD + h];
    }
    __syncthreads();

    {
        const int t = tid & 63, tau0 = tid >> 6;
        float Greg[16];
        #pragma unroll
        for (int k = 0; k < 16; k++) Greg[k] = 0.f;
        for (int s = 0; s < DS; s++) {
            float cv = CT[s * LC + t];
            #pragma unroll
            for (int k = 0; k < 16; k++) Greg[k] += cv * BW[(tau0 + 4 * k) * DS + s];
        }
        __syncthreads();
        float St = Sbuf[g * LSEQ + t0 + t];
        #pragma unroll
        for (int k = 0; k < 16; k++) {
            int tau = tau0 + 4 * k;
            float w = 0.f;
            if (tau <= t)
                w = expf(St - Sbuf[g * LSEQ + t0 + tau]) *
                    dt_soft[g * LSEQ + t0 + tau] * Greg[k];
            BW[tau * LC + t] = w;
        }
    }
    __syncthreads();

    const int h = tid & 127, tb = (tid >> 7) * 32;
    float y[32], T[32];
    #pragma unroll
    for (int j = 0; j < 32; j++) { y[j] = 0.f; T[j] = 0.f; }

    for (int tau = 0; tau < LC; tau++) {
        float xv = Xs[tau * HD + h];
        const float4* wrow = (const float4*)&BW[tau * LC + tb];
        #pragma unroll
        for (int q = 0; q < 8; q++) {
            float4 w4 = wrow[q];
            y[4*q+0] += w4.x * xv;
            y[4*q+1] += w4.y * xv;
            y[4*q+2] += w4.z * xv;
            y[4*q+3] += w4.w * xv;
        }
    }
    {
        const float* Hg = Hbuf + (size_t)(g * NC + c) * DS * HD;
        for (int s = 0; s < DS; s++) {
            float Hv = Hg[(size_t)s * HD + h];
            const float* crow = &CT[s * LC + tb];
            #pragma unroll
            for (int j = 0; j < 32; j++) T[j] += crow[j] * Hv;
        }
    }
    float Eprev = (c > 0) ? Ebuf[g * NC + c - 1] : 0.f;
    #pragma unroll
    for (int j = 0; j < 32; j++) {
        int t = tb + j;
        float St = Sbuf[g * LSEQ + t0 + t];
        float Dv = zq[(size_t)(t0 + t) * NZ + D_SSM + NG + g];
        y[j] += expf(St - Eprev) * T[j] + Dv * Xs[t * HD + h];
    }
    __syncthreads();
    #pragma unroll
    for (int j = 0; j < 32; j++) Xs[(tb + j) * HD + h] = y[j];
    __syncthreads();

    {
        int t = tid >> 2, q = tid & 3;
        float p = 0.f;
        for (int i = 0; i < 32; i++) {
            float v = Xs[t * HD + q * 32 + i];
            p += v * v;
        }
        red[t * 4 + q] = p;
    }
    __syncthreads();
    if (tid < LC) {
        float s2 = red[tid*4] + red[tid*4+1] + red[tid*4+2] + red[tid*4+3];
        sscale[tid] = rsqrtf(s2 * (1.f / HD) + EPS_RMS);
    }
    __syncthreads();

    float nw = norm_w[h];
    #pragma unroll
    for (int j = 0; j < 32; j++) {
        int t = tb + j;
        float zv = zq[(size_t)(t0 + t) * NZ + g * HD + h];
        size_t idx = (size_t)(t0 + t) * D_SSM + g * HD + h;
        float val = y[j] * sscale[t] * nw * siluf(zv);
        unsigned short hb = f2bf(val);
        ygH[idx] = hb;
        ygL[idx] = f2bf(val - bf2f(hb));
    }
}

extern "C" void kernel_launch(void* const* d_in, const int* in_sizes, int n_in,
                              void* d_out, int out_size, void* d_ws, size_t ws_size,
                              hipStream_t stream) {
    const float* hs      = (const float*)d_in[0];
    const float* W_qkv   = (const float*)d_in[1];
    const float* W_z     = (const float*)d_in[2];
    const float* W_a     = (const float*)d_in[3];
    const float* W_b     = (const float*)d_in[4];
    const float* conv_w  = (const float*)d_in[5];
    const float* W_out   = (const float*)d_in[6];
    const float* norm_w  = (const float*)d_in[7];
    const float* A_log   = (const float*)d_in[8];
    const float* dt_bias = (const float*)d_in[9];
    float* out = (float*)d_out;

    float* ws      = (float*)d_ws;
    float* xBC     = ws;                                   // 8,388,608 f
    float* zq      = xBC + (size_t)LSEQ * D_INNER;         // 4,325,376 f
    float* dt_soft = zq + (size_t)LSEQ * NZ;               // 32768 f
    float* Sbuf    = dt_soft + (size_t)NG * LSEQ;          // 32768 f
    float* Ebuf    = Sbuf + (size_t)NG * LSEQ;             // 512 f
    ushort* hsH    = (ushort*)(Ebuf + 512);                // 2,621,440 us
    ushort* hsL    = hsH + (size_t)LSEQ * HID;
    ushort* WH     = hsL + (size_t)LSEQ * HID;             // NBIG*HID = 31,784,960 us
    ushort* WL     = WH + (size_t)NBIG * HID;
    // phase-2 overlay on WH/WL region (dead after gemm_big256):
    float* xconv   = (float*)WH;                           // 8,388,608 f
    float* Sc      = xconv + (size_t)LSEQ * D_INNER;       // 4,194,304 f
    float* Hbuf    = Sc + (size_t)NG * NC * DS * HD;       // 4,194,304 f
    ushort* ygH    = (ushort*)(Hbuf + (size_t)NG * NC * DS * HD);  // 4,194,304 us
    ushort* ygL    = ygH + (size_t)LSEQ * D_SSM;
    ushort* WoH    = ygL + (size_t)LSEQ * D_SSM;           // 10,485,760 us
    ushort* WoL    = WoH + (size_t)HID * D_SSM;
    // phase-3 overlay: split-K partials [6][1024][2560] f32 = 15,728,640 f.
    // Lives in xconv+Sc+Hbuf (16,777,216 f) — all dead once chunk_output is
    // done; gemm_out_sk256 runs strictly after (stream order). ygH/ygL and
    // WoH/WoL are outside this span (round-6 aliasing audit).
    float* part    = xconv;

    // 1) all input planes in one kernel
    split_cvt_all<<<dim3(33440), dim3(256), 0, stream>>>(
        (const float4*)hs, (const float4*)W_qkv, (const float4*)W_z,
        (const float4*)W_b, (const float4*)W_a,
        (ushort4*)hsH, (ushort4*)hsL, (ushort4*)WH, (ushort4*)WL);

    // 2) merged projection GEMM: 196 blocks, proven form
    gemm_big256<<<dim3(GB_BLOCKS), dim3(512), 0, stream>>>(
        hsH, hsL, WH, WL, xBC, zq);

    // 3) conv+SiLU | W_out planes | dt-scan
    phase2_fused<<<dim3(CONV_BLKS + WOUT_BLKS + DT_BLKS), dim3(1024), 0, stream>>>(
        (const float4*)xBC, (const float4*)conv_w, (float4*)xconv,
        (const float4*)W_out, (ushort4*)WoH, (ushort4*)WoL,
        zq, A_log, dt_bias, dt_soft, Sbuf, Ebuf);

    dim3 blk(256);
    chunk_state<<<dim3(NG, NC), blk, 0, stream>>>(xconv, dt_soft, Sbuf, Ebuf, Sc);
    chunk_prefix<<<dim3(DS * HD / 256, NG), blk, 0, stream>>>(Sc, Ebuf, Hbuf);
    chunk_output<<<dim3(NG, NC), blk, 0, stream>>>(xconv, dt_soft, Sbuf, Ebuf,
                                                   Hbuf, zq, norm_w, ygH, ygL);

    // out = yg @ W_out^T: direct partial stores (no atomics), then reduce.
    gemm_out_sk256<<<dim3(240), dim3(512), 0, stream>>>(
        ygH, ygL, WoH, WoL, part);
    reduce6<<<dim3(LSEQ * HID / 4 / 256), blk, 0, stream>>>(
        (const float4*)part, (float4*)out);
}